// Round 9
// baseline (1449.982 us; speedup 1.0000x reference)
//
#include <hip/hip_runtime.h>
#include <math.h>

typedef __attribute__((ext_vector_type(8))) short short8;
typedef __attribute__((ext_vector_type(4))) float f32x4;

#define N_NODES 50000
#define NUM_REL 8
#define IN_DIM 128
#define HID 256
#define E_EDGES 1600000
#define M_DEC 200000
#define K1 1152
#define K2 2304
#define LN_EPS 1e-5f
#define NBUCK ((N_NODES + 63) >> 6)   /* 782 */

__device__ __forceinline__ float b2f(ushort u) {
    union { unsigned int i; float f; } v; v.i = ((unsigned int)u) << 16; return v.f;
}
__device__ __forceinline__ ushort f2b(float f) {
    union { float f; unsigned int i; } v; v.f = f;
    unsigned int r = v.i + 0x7FFFu + ((v.i >> 16) & 1u);
    return (ushort)(r >> 16);
}
__device__ __forceinline__ unsigned int pk2(ushort a, ushort b) {
    return (unsigned int)a | ((unsigned int)b << 16);
}
__device__ __forceinline__ float gelu_exact(float x) {
    return 0.5f * x * (1.0f + erff(x * 0.70710678118654752f));
}

// ---------------- CSR build ----------------
__global__ void count_kernel(const int* __restrict__ ei, int* __restrict__ cnt) {
    int e = blockIdx.x * 256 + threadIdx.x;
    if (e < E_EDGES) atomicAdd(&cnt[ei[E_EDGES + e]], 1);
}

__global__ void scan_kernel(const int* __restrict__ cnt, int* __restrict__ row_ptr, int n) {
    __shared__ int tsum[1024];
    const int t = threadIdx.x;
    const int CH = (n + 1023) / 1024;
    const int base = t * CH;
    int s = 0;
    for (int i = 0; i < CH; ++i) { int idx = base + i; if (idx < n) s += cnt[idx]; }
    tsum[t] = s;
    __syncthreads();
    for (int off = 1; off < 1024; off <<= 1) {
        int v = (t >= off) ? tsum[t - off] : 0;
        __syncthreads();
        tsum[t] += v;
        __syncthreads();
    }
    int run = tsum[t] - s;
    for (int i = 0; i < CH; ++i) {
        int idx = base + i;
        if (idx < n) { row_ptr[idx] = run; run += cnt[idx]; }
    }
    if (t == 1023) row_ptr[n] = tsum[1023];
}

__global__ void fill_kernel(const int* __restrict__ ei, const int* __restrict__ et,
                            const int* __restrict__ row_ptr, int* __restrict__ cursor,
                            unsigned int* __restrict__ epk) {
    int e = blockIdx.x * 256 + threadIdx.x;
    if (e >= E_EDGES) return;
    int src = ei[e];
    int dst = ei[E_EDGES + e];
    int r   = et[e];
    int pos = row_ptr[dst] + atomicAdd(&cursor[dst], 1);
    if (pos >= 0 && pos < E_EDGES)
        epk[pos] = (unsigned int)src | ((unsigned int)r << 16);
}

// ---------------- decode-edge locality sort (bucket by a>>6) ----------------
__global__ void ecount_kernel(const int* __restrict__ dec, int* __restrict__ bcnt) {
    int e = blockIdx.x * 256 + threadIdx.x;
    if (e >= M_DEC) return;
    int a = dec[(size_t)e * 2];
    if (a < 0) a = 0; if (a >= N_NODES) a = N_NODES - 1;
    atomicAdd(&bcnt[a >> 6], 1);
}

__global__ void efill_kernel(const int* __restrict__ dec, const int* __restrict__ bptr,
                             int* __restrict__ cur, int* __restrict__ perm) {
    int e = blockIdx.x * 256 + threadIdx.x;
    if (e >= M_DEC) return;
    int a = dec[(size_t)e * 2];
    if (a < 0) a = 0; if (a >= N_NODES) a = N_NODES - 1;
    int b = a >> 6;
    int pos = bptr[b] + atomicAdd(&cur[b], 1);
    if (pos >= 0 && pos < M_DEC) perm[pos] = e;
}

// ---------------- x fp32 -> bf16 table ----------------
__global__ void xconv_kernel(const float* __restrict__ x, ushort* __restrict__ xb) {
    int i = blockIdx.x * 256 + threadIdx.x;
    if ((size_t)i * 4 >= (size_t)N_NODES * IN_DIM) return;
    float4 v = *(const float4*)(x + (size_t)i * 4);
    uint2 o;
    o.x = pk2(f2b(v.x), f2b(v.y));
    o.y = pk2(f2b(v.z), f2b(v.w));
    *(uint2*)(xb + (size_t)i * 4) = o;
}

// ---------------- weight packing: fp32 -> bf16 transposed Bt[n][k] ----------------
__global__ void pack_enc(const float* __restrict__ root1, const float* __restrict__ W1,
                         const float* __restrict__ root2, const float* __restrict__ W2,
                         ushort* __restrict__ B1t, ushort* __restrict__ B2t) {
    int idx = blockIdx.x * 256 + threadIdx.x;
    const int n1 = HID * K1;
    if (idx < n1) {
        int n = idx / K1, k = idx % K1;
        float v;
        if (k < IN_DIM) v = root1[k * HID + n];
        else { int kk = k - IN_DIM; v = W1[(size_t)(kk >> 7) * IN_DIM * HID + (kk & 127) * HID + n]; }
        B1t[(size_t)n * K1 + k] = f2b(v);
    } else {
        int j = idx - n1;
        if (j >= HID * K2) return;
        int n = j / K2, k = j % K2;
        float v;
        if (k < HID) v = root2[k * HID + n];
        else { int kk = k - HID; v = W2[(size_t)(kk >> 8) * HID * HID + (kk & 255) * HID + n]; }
        B2t[(size_t)n * K2 + k] = f2b(v);
    }
}

__global__ void pack_mlp(const float* __restrict__ mw1, const float* __restrict__ mw2,
                         ushort* __restrict__ wuvt, ushort* __restrict__ w2t) {
    int idx = blockIdx.x * 256 + threadIdx.x;
    const int n1 = 512 * 256;
    if (idx < n1) {
        int n = idx / 256, k = idx % 256;
        float v = (n < 256) ? mw1[(size_t)k * 256 + n] : mw1[(size_t)(256 + k) * 256 + (n - 256)];
        wuvt[(size_t)n * 256 + k] = f2b(v);
    } else {
        int j = idx - n1;
        if (j >= 128 * 256) return;
        int n = j / 256, k = j % 256;
        w2t[n * 256 + k] = f2b(mw2[k * 128 + n]);
    }
}

// ---------------- aggregation: wave-per-node, NAMED register accumulators ----------------
#define C1(R) case R: a##R.x += f0; a##R.y += f1; c##R++; break;
#define E1(R) { float inv = c##R > 0 ? 1.f / (float)c##R : 0.f; \
                *(unsigned int*)(Arow + IN_DIM + R * IN_DIM + 2 * lane) = \
                    pk2(f2b(a##R.x * inv), f2b(a##R.y * inv)); }

__global__ __launch_bounds__(256) void agg1_kernel(const ushort* __restrict__ xb,
                                                   const int* __restrict__ row_ptr,
                                                   const unsigned int* __restrict__ epk,
                                                   ushort* __restrict__ Achunk, int n0, int m) {
    const int w = threadIdx.x >> 6, lane = threadIdx.x & 63;
    const int local = blockIdx.x * 4 + w;
    if (local >= m) return;
    const int n = n0 + local;
    float2 a0 = {0,0}, a1 = {0,0}, a2 = {0,0}, a3 = {0,0};
    float2 a4 = {0,0}, a5 = {0,0}, a6 = {0,0}, a7 = {0,0};
    int c0 = 0, c1 = 0, c2 = 0, c3 = 0, c4 = 0, c5 = 0, c6 = 0, c7 = 0;
    int beg = row_ptr[n], end = row_ptr[n + 1];
    if (beg < 0) beg = 0;
    if (end > E_EDGES) end = E_EDGES;
    const ushort* xbb = xb + 2 * lane;
    int e = beg;
    for (; e + 1 < end; e += 2) {
        unsigned int p0 = epk[e], p1 = epk[e + 1];
        unsigned int u0 = *(const unsigned int*)(xbb + (size_t)(p0 & 0xFFFFu) * IN_DIM);
        unsigned int u1 = *(const unsigned int*)(xbb + (size_t)(p1 & 0xFFFFu) * IN_DIM);
        int r0 = (__builtin_amdgcn_readfirstlane((int)p0) >> 16) & 7;
        int r1 = (__builtin_amdgcn_readfirstlane((int)p1) >> 16) & 7;
        {
            float f0 = b2f((ushort)(u0 & 0xFFFFu)), f1 = b2f((ushort)(u0 >> 16));
            switch (r0) { C1(0) C1(1) C1(2) C1(3) C1(4) C1(5) C1(6) C1(7) }
        }
        {
            float f0 = b2f((ushort)(u1 & 0xFFFFu)), f1 = b2f((ushort)(u1 >> 16));
            switch (r1) { C1(0) C1(1) C1(2) C1(3) C1(4) C1(5) C1(6) C1(7) }
        }
    }
    for (; e < end; ++e) {
        unsigned int p = epk[e];
        unsigned int u = *(const unsigned int*)(xbb + (size_t)(p & 0xFFFFu) * IN_DIM);
        int r = (__builtin_amdgcn_readfirstlane((int)p) >> 16) & 7;
        float f0 = b2f((ushort)(u & 0xFFFFu)), f1 = b2f((ushort)(u >> 16));
        switch (r) { C1(0) C1(1) C1(2) C1(3) C1(4) C1(5) C1(6) C1(7) }
    }
    ushort* Arow = Achunk + (size_t)local * K1;
    *(unsigned int*)(Arow + 2 * lane) = *(const unsigned int*)(xb + (size_t)n * IN_DIM + 2 * lane);
    E1(0) E1(1) E1(2) E1(3) E1(4) E1(5) E1(6) E1(7)
}

#define C2(R) case R: a##R += f; c##R++; break;
#define E2(R) { float inv = c##R > 0 ? 1.f / (float)c##R : 0.f; uint2 o; \
                o.x = pk2(f2b(a##R[0] * inv), f2b(a##R[1] * inv)); \
                o.y = pk2(f2b(a##R[2] * inv), f2b(a##R[3] * inv)); \
                *(uint2*)(Arow + HID + R * HID + 4 * lane) = o; }

__global__ __launch_bounds__(256) void agg2_kernel(const ushort* __restrict__ h1,
                                                   const int* __restrict__ row_ptr,
                                                   const unsigned int* __restrict__ epk,
                                                   ushort* __restrict__ Achunk, int n0, int m) {
    const int w = threadIdx.x >> 6, lane = threadIdx.x & 63;
    const int local = blockIdx.x * 4 + w;
    if (local >= m) return;
    const int n = n0 + local;
    f32x4 a0 = {0,0,0,0}, a1 = {0,0,0,0}, a2 = {0,0,0,0}, a3 = {0,0,0,0};
    f32x4 a4 = {0,0,0,0}, a5 = {0,0,0,0}, a6 = {0,0,0,0}, a7 = {0,0,0,0};
    int c0 = 0, c1 = 0, c2 = 0, c3 = 0, c4 = 0, c5 = 0, c6 = 0, c7 = 0;
    int beg = row_ptr[n], end = row_ptr[n + 1];
    if (beg < 0) beg = 0;
    if (end > E_EDGES) end = E_EDGES;
    const ushort* hb = h1 + 4 * lane;
    int e = beg;
    for (; e + 1 < end; e += 2) {
        unsigned int p0 = epk[e], p1 = epk[e + 1];
        uint2 u0 = *(const uint2*)(hb + (size_t)(p0 & 0xFFFFu) * HID);
        uint2 u1 = *(const uint2*)(hb + (size_t)(p1 & 0xFFFFu) * HID);
        int r0 = (__builtin_amdgcn_readfirstlane((int)p0) >> 16) & 7;
        int r1 = (__builtin_amdgcn_readfirstlane((int)p1) >> 16) & 7;
        {
            f32x4 f;
            f[0] = b2f((ushort)(u0.x & 0xFFFFu)); f[1] = b2f((ushort)(u0.x >> 16));
            f[2] = b2f((ushort)(u0.y & 0xFFFFu)); f[3] = b2f((ushort)(u0.y >> 16));
            switch (r0) { C2(0) C2(1) C2(2) C2(3) C2(4) C2(5) C2(6) C2(7) }
        }
        {
            f32x4 f;
            f[0] = b2f((ushort)(u1.x & 0xFFFFu)); f[1] = b2f((ushort)(u1.x >> 16));
            f[2] = b2f((ushort)(u1.y & 0xFFFFu)); f[3] = b2f((ushort)(u1.y >> 16));
            switch (r1) { C2(0) C2(1) C2(2) C2(3) C2(4) C2(5) C2(6) C2(7) }
        }
    }
    for (; e < end; ++e) {
        unsigned int p = epk[e];
        uint2 u0 = *(const uint2*)(hb + (size_t)(p & 0xFFFFu) * HID);
        int r = (__builtin_amdgcn_readfirstlane((int)p) >> 16) & 7;
        f32x4 f;
        f[0] = b2f((ushort)(u0.x & 0xFFFFu)); f[1] = b2f((ushort)(u0.x >> 16));
        f[2] = b2f((ushort)(u0.y & 0xFFFFu)); f[3] = b2f((ushort)(u0.y >> 16));
        switch (r) { C2(0) C2(1) C2(2) C2(3) C2(4) C2(5) C2(6) C2(7) }
    }
    ushort* Arow = Achunk + (size_t)local * K2;
    *(uint2*)(Arow + 4 * lane) = *(const uint2*)(h1 + (size_t)n * HID + 4 * lane);
    E2(0) E2(1) E2(2) E2(3) E2(4) E2(5) E2(6) E2(7)
}

// ---------------- GEMM 32x256 tile, A-only LDS, B direct from global (L2-hot) ------------
// + fused bias/ReLU/LN(/residual) epilogue. g==nullptr -> plain bf16 store.
__global__ __launch_bounds__(256) void gemm_fused(
    const ushort* __restrict__ A, const ushort* __restrict__ Bt,
    int lda, int M, int K,
    const float* __restrict__ bias, const float* __restrict__ g,
    const float* __restrict__ bvec, const ushort* __restrict__ resid,
    ushort* __restrict__ outp, int ldc, int rowOff) {
    __shared__ __align__(16) ushort As[32][72];
    __shared__ float partS[32][4];
    __shared__ float partQ[32][4];
    __shared__ float muS[32], rsS[32];
    const int tid = threadIdx.x;
    const int wave = tid >> 6, lane = tid & 63;
    const int cc = lane & 15, qd = lane >> 4;
    const int lk = qd * 8;
    const int row0 = blockIdx.x * 32;
    const int colBase = blockIdx.y * 256;
    const int wn = wave * 64;
    const int sr = tid >> 3, skc = (tid & 7) * 8;       // A staging: 1 uint4/thread
    f32x4 acc[2][4];
#pragma unroll
    for (int i = 0; i < 2; ++i)
#pragma unroll
        for (int j = 0; j < 4; ++j) acc[i][j] = (f32x4){0.f, 0.f, 0.f, 0.f};

    const ushort* bbase = Bt + (size_t)(colBase + wn + cc) * K;   // rows wn+cc, +16, +32, +48

    for (int k0 = 0; k0 < K; k0 += 64) {
        {
            uint4 va = make_uint4(0u, 0u, 0u, 0u);
            int gr = row0 + sr;
            if (gr < M) va = *(const uint4*)(A + (size_t)gr * lda + k0 + skc);
            *(uint4*)&As[sr][skc] = va;
        }
        __syncthreads();
#pragma unroll
        for (int kk = 0; kk < 2; ++kk) {
            short8 af[2], bfv[4];
#pragma unroll
            for (int i = 0; i < 2; ++i) af[i] = *(const short8*)&As[i * 16 + cc][kk * 32 + lk];
#pragma unroll
            for (int j = 0; j < 4; ++j)
                bfv[j] = *(const short8*)(bbase + (size_t)j * 16 * K + k0 + kk * 32 + lk);
#pragma unroll
            for (int i = 0; i < 2; ++i)
#pragma unroll
                for (int j = 0; j < 4; ++j)
                    acc[i][j] = __builtin_amdgcn_mfma_f32_16x16x32_bf16(af[i], bfv[j], acc[i][j], 0, 0, 0);
        }
        __syncthreads();
    }

    if (g) {
#pragma unroll
        for (int j = 0; j < 4; ++j) {
            float bcol = bias[wn + j * 16 + cc];
#pragma unroll
            for (int i = 0; i < 2; ++i)
#pragma unroll
                for (int r = 0; r < 4; ++r)
                    acc[i][j][r] = fmaxf(acc[i][j][r] + bcol, 0.f);
        }
#pragma unroll
        for (int i = 0; i < 2; ++i)
#pragma unroll
            for (int r = 0; r < 4; ++r) {
                float s = acc[i][0][r] + acc[i][1][r] + acc[i][2][r] + acc[i][3][r];
                float q = acc[i][0][r] * acc[i][0][r] + acc[i][1][r] * acc[i][1][r]
                        + acc[i][2][r] * acc[i][2][r] + acc[i][3][r] * acc[i][3][r];
#pragma unroll
                for (int off = 1; off <= 8; off <<= 1) {
                    s += __shfl_xor(s, off, 64);
                    q += __shfl_xor(q, off, 64);
                }
                if (cc == 0) {
                    int row = i * 16 + qd * 4 + r;
                    partS[row][wave] = s;
                    partQ[row][wave] = q;
                }
            }
        __syncthreads();
        if (tid < 32) {
            float S = partS[tid][0] + partS[tid][1] + partS[tid][2] + partS[tid][3];
            float Q = partQ[tid][0] + partQ[tid][1] + partQ[tid][2] + partQ[tid][3];
            float mu = S * (1.f / 256.f);
            float var = Q * (1.f / 256.f) - mu * mu;
            muS[tid] = mu;
            rsS[tid] = rsqrtf(fmaxf(var, 0.f) + LN_EPS);
        }
        __syncthreads();
#pragma unroll
        for (int i = 0; i < 2; ++i)
#pragma unroll
            for (int r = 0; r < 4; ++r) {
                int row = i * 16 + qd * 4 + r;
                int grow = row0 + row;
                if (grow >= M) continue;
                float mu = muS[row], rs = rsS[row];
                size_t base = (size_t)(rowOff + grow) * ldc;
#pragma unroll
                for (int j = 0; j < 4; ++j) {
                    int col = wn + j * 16 + cc;
                    float val = (acc[i][j][r] - mu) * rs * g[col] + bvec[col];
                    if (resid) val += b2f(resid[base + col]);
                    outp[base + col] = f2b(val);
                }
            }
    } else {
#pragma unroll
        for (int i = 0; i < 2; ++i)
#pragma unroll
            for (int r = 0; r < 4; ++r) {
                int grow = row0 + i * 16 + qd * 4 + r;
                if (grow >= M) continue;
                size_t base = (size_t)(rowOff + grow) * ldc;
#pragma unroll
                for (int j = 0; j < 4; ++j) {
                    int col = colBase + wn + j * 16 + cc;
                    outp[base + col] = f2b(acc[i][j][r]);
                }
            }
    }
}

// ---------------- edge decode (perm-ordered): z1=gelu(U[a]+V[b]+b1); z2=gelu(z1@w2); out=z2@w3+b3
__global__ __launch_bounds__(256) void edge_kernel(
    const ushort* __restrict__ uv, const int* __restrict__ dec, const int* __restrict__ perm,
    const float* __restrict__ b1, const ushort* __restrict__ w2t,
    const float* __restrict__ b2, const float* __restrict__ w3,
    const float* __restrict__ b3, float* __restrict__ outp, int M) {
    __shared__ __align__(16) ushort z1s[64][264];
    __shared__ __align__(16) ushort z2s[64][136];
    __shared__ float b1s[256], b2s[128], w3s[256];
    const int tid = threadIdx.x;
    const int wave = tid >> 6, lane = tid & 63;
    const int cc = lane & 15, qd = lane >> 4, lk = qd * 8, rr = qd * 4;
    const int e0 = blockIdx.x * 64;

    b1s[tid] = b1[tid];
    if (tid < 128) b2s[tid] = b2[tid];
    w3s[tid] = w3[tid];
    __syncthreads();

    {
        int e = tid >> 2, seg = tid & 3;
        int ge = perm[e0 + e];
        if (ge < 0) ge = 0; if (ge >= M) ge = M - 1;
        int a = dec[(size_t)ge * 2];
        int b = dec[(size_t)ge * 2 + 1];
        if (a < 0) a = 0; if (a >= N_NODES) a = N_NODES - 1;
        if (b < 0) b = 0; if (b >= N_NODES) b = N_NODES - 1;
        const ushort* up = uv + (size_t)a * 512;
        const ushort* vp = uv + (size_t)b * 512 + 256;
        int d0 = seg * 64;
#pragma unroll
        for (int c8 = 0; c8 < 8; ++c8) {
            int d = d0 + c8 * 8;
            short8 us = *(const short8*)(up + d);
            short8 vs = *(const short8*)(vp + d);
            short8 zs;
#pragma unroll
            for (int l = 0; l < 8; ++l) {
                float z = b2f((ushort)us[l]) + b2f((ushort)vs[l]) + b1s[d + l];
                zs[l] = (short)f2b(gelu_exact(z));
            }
            *(short8*)&z1s[e][d] = zs;
        }
    }
    __syncthreads();

    f32x4 acc[4][2];
#pragma unroll
    for (int i = 0; i < 4; ++i)
#pragma unroll
        for (int j = 0; j < 2; ++j) acc[i][j] = (f32x4){0.f, 0.f, 0.f, 0.f};
    const int n0 = wave * 32;
#pragma unroll
    for (int ks = 0; ks < 8; ++ks) {
        short8 af[4], bfv[2];
#pragma unroll
        for (int i = 0; i < 4; ++i) af[i] = *(const short8*)&z1s[i * 16 + cc][ks * 32 + lk];
#pragma unroll
        for (int j = 0; j < 2; ++j)
            bfv[j] = *(const short8*)(w2t + (size_t)(n0 + j * 16 + cc) * 256 + ks * 32 + lk);
#pragma unroll
        for (int i = 0; i < 4; ++i)
#pragma unroll
            for (int j = 0; j < 2; ++j)
                acc[i][j] = __builtin_amdgcn_mfma_f32_16x16x32_bf16(af[i], bfv[j], acc[i][j], 0, 0, 0);
    }
#pragma unroll
    for (int i = 0; i < 4; ++i)
#pragma unroll
        for (int j = 0; j < 2; ++j)
#pragma unroll
            for (int r = 0; r < 4; ++r) {
                int m = i * 16 + rr + r;
                int n = n0 + j * 16 + cc;
                z2s[m][n] = f2b(gelu_exact(acc[i][j][r] + b2s[n]));
            }
    __syncthreads();

    if (tid < 128) {
        int e = tid >> 1, c = tid & 1;
        float s = b3[c];
        for (int k = 0; k < 128; ++k) s += b2f(z2s[e][k]) * w3s[k * 2 + c];
        int ge = perm[e0 + e];
        if (ge >= 0 && ge < M) outp[(size_t)ge * 2 + c] = s;
    }
}

// ---------------- launch ----------------
extern "C" void kernel_launch(void* const* d_in, const int* in_sizes, int n_in,
                              void* d_out, int out_size, void* d_ws, size_t ws_size,
                              hipStream_t stream) {
    const float* x          = (const float*)d_in[0];
    const int*   edge_index = (const int*)d_in[1];
    const int*   edge_type  = (const int*)d_in[2];
    const int*   dec_edges  = (const int*)d_in[3];
    const float* W1         = (const float*)d_in[4];
    const float* root1      = (const float*)d_in[5];
    const float* b1         = (const float*)d_in[6];
    const float* W2         = (const float*)d_in[7];
    const float* root2      = (const float*)d_in[8];
    const float* b2         = (const float*)d_in[9];
    const float* ln1_g      = (const float*)d_in[10];
    const float* ln1_b      = (const float*)d_in[11];
    const float* ln2_g      = (const float*)d_in[12];
    const float* ln2_b      = (const float*)d_in[13];
    const float* mlp_w1     = (const float*)d_in[14];
    const float* mlp_b1     = (const float*)d_in[15];
    const float* mlp_w2     = (const float*)d_in[16];
    const float* mlp_b2     = (const float*)d_in[17];
    const float* mlp_w3     = (const float*)d_in[18];
    const float* mlp_b3     = (const float*)d_in[19];

    char* ws = (char*)d_ws;
    size_t off = 0;
    auto alloc = [&](size_t bytes) {
        void* p = ws + off;
        off += (bytes + 255) & ~(size_t)255;
        return p;
    };
    unsigned int* epk     = (unsigned int*)alloc((size_t)E_EDGES * 4);
    int*          row_ptr = (int*)alloc((size_t)(N_NODES + 1) * 4);
    int*          tmp     = (int*)alloc((size_t)N_NODES * 4);
    int*          bptr    = (int*)alloc((size_t)(NBUCK + 1) * 4);
    int*          perm    = (int*)alloc((size_t)M_DEC * 4);
    ushort*       B1t     = (ushort*)alloc((size_t)HID * K1 * 2);
    ushort*       B2t     = (ushort*)alloc((size_t)HID * K2 * 2);
    ushort*       wuvt    = (ushort*)alloc((size_t)512 * 256 * 2);
    ushort*       w2t     = (ushort*)alloc((size_t)128 * 256 * 2);
    ushort*       xb      = (ushort*)alloc((size_t)N_NODES * IN_DIM * 2);
    ushort*       hfin    = (ushort*)alloc((size_t)N_NODES * HID * 2);

    size_t regionOff = off;
    ushort* h1ln  = (ushort*)(ws + regionOff);
    ushort* uvbuf = h1ln;                       // alias (uv live after h1ln dead)
    size_t h1b = (((size_t)N_NODES * HID * 2) + 255) & ~(size_t)255;
    ushort* Achunk = (ushort*)(ws + regionOff + h1b);
    long long chunkB = (long long)ws_size - (long long)(regionOff + h1b);
    int chunk = 64;
    if (chunkB > 0) {
        long long c = chunkB / ((long long)K2 * 2);
        if (c > N_NODES) c = N_NODES;
        c &= ~63LL;
        if (c >= 64) chunk = (int)c;
    }

    // CSR build
    hipMemsetAsync(tmp, 0, (size_t)N_NODES * 4, stream);
    count_kernel<<<(E_EDGES + 255) / 256, 256, 0, stream>>>(edge_index, tmp);
    scan_kernel<<<1, 1024, 0, stream>>>(tmp, row_ptr, N_NODES);
    hipMemsetAsync(tmp, 0, (size_t)N_NODES * 4, stream);
    fill_kernel<<<(E_EDGES + 255) / 256, 256, 0, stream>>>(edge_index, edge_type, row_ptr, tmp, epk);

    // decode-edge locality sort
    hipMemsetAsync(tmp, 0, (size_t)NBUCK * 4, stream);
    ecount_kernel<<<(M_DEC + 255) / 256, 256, 0, stream>>>(dec_edges, tmp);
    scan_kernel<<<1, 1024, 0, stream>>>(tmp, bptr, NBUCK);
    hipMemsetAsync(tmp, 0, (size_t)NBUCK * 4, stream);
    efill_kernel<<<(M_DEC + 255) / 256, 256, 0, stream>>>(dec_edges, bptr, tmp, perm);

    // x -> bf16 table, weight packs
    xconv_kernel<<<(N_NODES * IN_DIM / 4 + 255) / 256, 256, 0, stream>>>(x, xb);
    pack_enc<<<(HID * K1 + HID * K2 + 255) / 256, 256, 0, stream>>>(root1, W1, root2, W2, B1t, B2t);
    pack_mlp<<<(512 * 256 + 128 * 256 + 255) / 256, 256, 0, stream>>>(mlp_w1, mlp_w2, wuvt, w2t);

    // conv1
    for (int n0 = 0; n0 < N_NODES; n0 += chunk) {
        int m = N_NODES - n0; if (m > chunk) m = chunk;
        agg1_kernel<<<(m + 3) / 4, 256, 0, stream>>>(xb, row_ptr, epk, Achunk, n0, m);
        gemm_fused<<<dim3((m + 31) / 32, 1), 256, 0, stream>>>(
            Achunk, B1t, K1, m, K1, b1, ln1_g, ln1_b, nullptr, h1ln, HID, n0);
    }
    // conv2 (+h1 residual)
    for (int n0 = 0; n0 < N_NODES; n0 += chunk) {
        int m = N_NODES - n0; if (m > chunk) m = chunk;
        agg2_kernel<<<(m + 3) / 4, 256, 0, stream>>>(h1ln, row_ptr, epk, Achunk, n0, m);
        gemm_fused<<<dim3((m + 31) / 32, 1), 256, 0, stream>>>(
            Achunk, B2t, K2, m, K2, b2, ln2_g, ln2_b, h1ln, hfin, HID, n0);
    }

    // U|V = hfin @ [W1_top | W1_bot]
    gemm_fused<<<dim3((N_NODES + 31) / 32, 2), 256, 0, stream>>>(
        hfin, wuvt, HID, N_NODES, HID, nullptr, nullptr, nullptr, nullptr, uvbuf, 512, 0);

    // edge decode
    edge_kernel<<<(M_DEC + 63) / 64, 256, 0, stream>>>(
        uvbuf, dec_edges, perm, mlp_b1, w2t, mlp_b2, mlp_w3, mlp_b3, (float*)d_out, M_DEC);
}

// Round 10
// 1257.726 us; speedup vs baseline: 1.1529x; 1.1529x over previous
//
#include <hip/hip_runtime.h>
#include <math.h>

typedef __attribute__((ext_vector_type(8))) short short8;
typedef __attribute__((ext_vector_type(4))) float f32x4;

#define N_NODES 50000
#define NUM_REL 8
#define IN_DIM 128
#define HID 256
#define E_EDGES 1600000
#define M_DEC 200000
#define K1 1152
#define K2 2304
#define LN_EPS 1e-5f
#define NBUCK ((N_NODES + 63) >> 6)   /* 782 */

__device__ __forceinline__ float b2f(ushort u) {
    union { unsigned int i; float f; } v; v.i = ((unsigned int)u) << 16; return v.f;
}
__device__ __forceinline__ ushort f2b(float f) {
    union { float f; unsigned int i; } v; v.f = f;
    unsigned int r = v.i + 0x7FFFu + ((v.i >> 16) & 1u);
    return (ushort)(r >> 16);
}
__device__ __forceinline__ unsigned int pk2(ushort a, ushort b) {
    return (unsigned int)a | ((unsigned int)b << 16);
}
__device__ __forceinline__ float gelu_exact(float x) {
    return 0.5f * x * (1.0f + erff(x * 0.70710678118654752f));
}

// ---------------- CSR build ----------------
__global__ void count_kernel(const int* __restrict__ ei, int* __restrict__ cnt) {
    int e = blockIdx.x * 256 + threadIdx.x;
    if (e < E_EDGES) atomicAdd(&cnt[ei[E_EDGES + e]], 1);
}

__global__ void scan_kernel(const int* __restrict__ cnt, int* __restrict__ row_ptr, int n) {
    __shared__ int tsum[1024];
    const int t = threadIdx.x;
    const int CH = (n + 1023) / 1024;
    const int base = t * CH;
    int s = 0;
    for (int i = 0; i < CH; ++i) { int idx = base + i; if (idx < n) s += cnt[idx]; }
    tsum[t] = s;
    __syncthreads();
    for (int off = 1; off < 1024; off <<= 1) {
        int v = (t >= off) ? tsum[t - off] : 0;
        __syncthreads();
        tsum[t] += v;
        __syncthreads();
    }
    int run = tsum[t] - s;
    for (int i = 0; i < CH; ++i) {
        int idx = base + i;
        if (idx < n) { row_ptr[idx] = run; run += cnt[idx]; }
    }
    if (t == 1023) row_ptr[n] = tsum[1023];
}

__global__ void fill_kernel(const int* __restrict__ ei, const int* __restrict__ et,
                            const int* __restrict__ row_ptr, int* __restrict__ cursor,
                            unsigned int* __restrict__ epk) {
    int e = blockIdx.x * 256 + threadIdx.x;
    if (e >= E_EDGES) return;
    int src = ei[e];
    int dst = ei[E_EDGES + e];
    int r   = et[e];
    int pos = row_ptr[dst] + atomicAdd(&cursor[dst], 1);
    if (pos >= 0 && pos < E_EDGES)
        epk[pos] = (unsigned int)src | ((unsigned int)r << 16);
}

// ---------------- decode-edge locality sort (bucket by a>>6) ----------------
__global__ void ecount_kernel(const int* __restrict__ dec, int* __restrict__ bcnt) {
    int e = blockIdx.x * 256 + threadIdx.x;
    if (e >= M_DEC) return;
    int a = dec[(size_t)e * 2];
    if (a < 0) a = 0; if (a >= N_NODES) a = N_NODES - 1;
    atomicAdd(&bcnt[a >> 6], 1);
}

__global__ void efill_kernel(const int* __restrict__ dec, const int* __restrict__ bptr,
                             int* __restrict__ cur, int* __restrict__ perm) {
    int e = blockIdx.x * 256 + threadIdx.x;
    if (e >= M_DEC) return;
    int a = dec[(size_t)e * 2];
    if (a < 0) a = 0; if (a >= N_NODES) a = N_NODES - 1;
    int b = a >> 6;
    int pos = bptr[b] + atomicAdd(&cur[b], 1);
    if (pos >= 0 && pos < M_DEC) perm[pos] = e;
}

// ---------------- x fp32 -> bf16 table ----------------
__global__ void xconv_kernel(const float* __restrict__ x, ushort* __restrict__ xb) {
    int i = blockIdx.x * 256 + threadIdx.x;
    if ((size_t)i * 4 >= (size_t)N_NODES * IN_DIM) return;
    float4 v = *(const float4*)(x + (size_t)i * 4);
    uint2 o;
    o.x = pk2(f2b(v.x), f2b(v.y));
    o.y = pk2(f2b(v.z), f2b(v.w));
    *(uint2*)(xb + (size_t)i * 4) = o;
}

// ---------------- weight packing: fp32 -> bf16 transposed Bt[n][k] ----------------
__global__ void pack_enc(const float* __restrict__ root1, const float* __restrict__ W1,
                         const float* __restrict__ root2, const float* __restrict__ W2,
                         ushort* __restrict__ B1t, ushort* __restrict__ B2t) {
    int idx = blockIdx.x * 256 + threadIdx.x;
    const int n1 = HID * K1;
    if (idx < n1) {
        int n = idx / K1, k = idx % K1;
        float v;
        if (k < IN_DIM) v = root1[k * HID + n];
        else { int kk = k - IN_DIM; v = W1[(size_t)(kk >> 7) * IN_DIM * HID + (kk & 127) * HID + n]; }
        B1t[(size_t)n * K1 + k] = f2b(v);
    } else {
        int j = idx - n1;
        if (j >= HID * K2) return;
        int n = j / K2, k = j % K2;
        float v;
        if (k < HID) v = root2[k * HID + n];
        else { int kk = k - HID; v = W2[(size_t)(kk >> 8) * HID * HID + (kk & 255) * HID + n]; }
        B2t[(size_t)n * K2 + k] = f2b(v);
    }
}

__global__ void pack_mlp(const float* __restrict__ mw1, const float* __restrict__ mw2,
                         ushort* __restrict__ wuvt, ushort* __restrict__ w2t) {
    int idx = blockIdx.x * 256 + threadIdx.x;
    const int n1 = 512 * 256;
    if (idx < n1) {
        int n = idx / 256, k = idx % 256;
        float v = (n < 256) ? mw1[(size_t)k * 256 + n] : mw1[(size_t)(256 + k) * 256 + (n - 256)];
        wuvt[(size_t)n * 256 + k] = f2b(v);
    } else {
        int j = idx - n1;
        if (j >= 128 * 256) return;
        int n = j / 256, k = j % 256;
        w2t[n * 256 + k] = f2b(mw2[k * 128 + n]);
    }
}

// ---------------- aggregation: wave-per-node, NAMED register accumulators ----------------
#define C1(R) case R: a##R.x += f0; a##R.y += f1; c##R++; break;
#define E1(R) { float inv = c##R > 0 ? 1.f / (float)c##R : 0.f; \
                *(unsigned int*)(Arow + IN_DIM + R * IN_DIM + 2 * lane) = \
                    pk2(f2b(a##R.x * inv), f2b(a##R.y * inv)); }

__global__ __launch_bounds__(256) void agg1_kernel(const ushort* __restrict__ xb,
                                                   const int* __restrict__ row_ptr,
                                                   const unsigned int* __restrict__ epk,
                                                   ushort* __restrict__ Achunk, int n0, int m) {
    const int w = threadIdx.x >> 6, lane = threadIdx.x & 63;
    const int local = blockIdx.x * 4 + w;
    if (local >= m) return;
    const int n = n0 + local;
    float2 a0 = {0,0}, a1 = {0,0}, a2 = {0,0}, a3 = {0,0};
    float2 a4 = {0,0}, a5 = {0,0}, a6 = {0,0}, a7 = {0,0};
    int c0 = 0, c1 = 0, c2 = 0, c3 = 0, c4 = 0, c5 = 0, c6 = 0, c7 = 0;
    int beg = row_ptr[n], end = row_ptr[n + 1];
    if (beg < 0) beg = 0;
    if (end > E_EDGES) end = E_EDGES;
    const ushort* xbb = xb + 2 * lane;
    int e = beg;
    for (; e + 1 < end; e += 2) {
        unsigned int p0 = epk[e], p1 = epk[e + 1];
        unsigned int u0 = *(const unsigned int*)(xbb + (size_t)(p0 & 0xFFFFu) * IN_DIM);
        unsigned int u1 = *(const unsigned int*)(xbb + (size_t)(p1 & 0xFFFFu) * IN_DIM);
        int r0 = (__builtin_amdgcn_readfirstlane((int)p0) >> 16) & 7;
        int r1 = (__builtin_amdgcn_readfirstlane((int)p1) >> 16) & 7;
        {
            float f0 = b2f((ushort)(u0 & 0xFFFFu)), f1 = b2f((ushort)(u0 >> 16));
            switch (r0) { C1(0) C1(1) C1(2) C1(3) C1(4) C1(5) C1(6) C1(7) }
        }
        {
            float f0 = b2f((ushort)(u1 & 0xFFFFu)), f1 = b2f((ushort)(u1 >> 16));
            switch (r1) { C1(0) C1(1) C1(2) C1(3) C1(4) C1(5) C1(6) C1(7) }
        }
    }
    for (; e < end; ++e) {
        unsigned int p = epk[e];
        unsigned int u = *(const unsigned int*)(xbb + (size_t)(p & 0xFFFFu) * IN_DIM);
        int r = (__builtin_amdgcn_readfirstlane((int)p) >> 16) & 7;
        float f0 = b2f((ushort)(u & 0xFFFFu)), f1 = b2f((ushort)(u >> 16));
        switch (r) { C1(0) C1(1) C1(2) C1(3) C1(4) C1(5) C1(6) C1(7) }
    }
    ushort* Arow = Achunk + (size_t)local * K1;
    *(unsigned int*)(Arow + 2 * lane) = *(const unsigned int*)(xb + (size_t)n * IN_DIM + 2 * lane);
    E1(0) E1(1) E1(2) E1(3) E1(4) E1(5) E1(6) E1(7)
}

#define C2(R) case R: a##R += f; c##R++; break;
#define E2(R) { float inv = c##R > 0 ? 1.f / (float)c##R : 0.f; uint2 o; \
                o.x = pk2(f2b(a##R[0] * inv), f2b(a##R[1] * inv)); \
                o.y = pk2(f2b(a##R[2] * inv), f2b(a##R[3] * inv)); \
                *(uint2*)(Arow + HID + R * HID + 4 * lane) = o; }

__global__ __launch_bounds__(256) void agg2_kernel(const ushort* __restrict__ h1,
                                                   const int* __restrict__ row_ptr,
                                                   const unsigned int* __restrict__ epk,
                                                   ushort* __restrict__ Achunk, int n0, int m) {
    const int w = threadIdx.x >> 6, lane = threadIdx.x & 63;
    const int local = blockIdx.x * 4 + w;
    if (local >= m) return;
    const int n = n0 + local;
    f32x4 a0 = {0,0,0,0}, a1 = {0,0,0,0}, a2 = {0,0,0,0}, a3 = {0,0,0,0};
    f32x4 a4 = {0,0,0,0}, a5 = {0,0,0,0}, a6 = {0,0,0,0}, a7 = {0,0,0,0};
    int c0 = 0, c1 = 0, c2 = 0, c3 = 0, c4 = 0, c5 = 0, c6 = 0, c7 = 0;
    int beg = row_ptr[n], end = row_ptr[n + 1];
    if (beg < 0) beg = 0;
    if (end > E_EDGES) end = E_EDGES;
    const ushort* hb = h1 + 4 * lane;
    int e = beg;
    for (; e + 1 < end; e += 2) {
        unsigned int p0 = epk[e], p1 = epk[e + 1];
        uint2 u0 = *(const uint2*)(hb + (size_t)(p0 & 0xFFFFu) * HID);
        uint2 u1 = *(const uint2*)(hb + (size_t)(p1 & 0xFFFFu) * HID);
        int r0 = (__builtin_amdgcn_readfirstlane((int)p0) >> 16) & 7;
        int r1 = (__builtin_amdgcn_readfirstlane((int)p1) >> 16) & 7;
        {
            f32x4 f;
            f[0] = b2f((ushort)(u0.x & 0xFFFFu)); f[1] = b2f((ushort)(u0.x >> 16));
            f[2] = b2f((ushort)(u0.y & 0xFFFFu)); f[3] = b2f((ushort)(u0.y >> 16));
            switch (r0) { C2(0) C2(1) C2(2) C2(3) C2(4) C2(5) C2(6) C2(7) }
        }
        {
            f32x4 f;
            f[0] = b2f((ushort)(u1.x & 0xFFFFu)); f[1] = b2f((ushort)(u1.x >> 16));
            f[2] = b2f((ushort)(u1.y & 0xFFFFu)); f[3] = b2f((ushort)(u1.y >> 16));
            switch (r1) { C2(0) C2(1) C2(2) C2(3) C2(4) C2(5) C2(6) C2(7) }
        }
    }
    for (; e < end; ++e) {
        unsigned int p = epk[e];
        uint2 u0 = *(const uint2*)(hb + (size_t)(p & 0xFFFFu) * HID);
        int r = (__builtin_amdgcn_readfirstlane((int)p) >> 16) & 7;
        f32x4 f;
        f[0] = b2f((ushort)(u0.x & 0xFFFFu)); f[1] = b2f((ushort)(u0.x >> 16));
        f[2] = b2f((ushort)(u0.y & 0xFFFFu)); f[3] = b2f((ushort)(u0.y >> 16));
        switch (r) { C2(0) C2(1) C2(2) C2(3) C2(4) C2(5) C2(6) C2(7) }
    }
    ushort* Arow = Achunk + (size_t)local * K2;
    *(uint2*)(Arow + 4 * lane) = *(const uint2*)(h1 + (size_t)n * HID + 4 * lane);
    E2(0) E2(1) E2(2) E2(3) E2(4) E2(5) E2(6) E2(7)
}

// ---------------- GEMM 32x256 tile, A+B in LDS (padded), fused LN epilogue ----------------
// ~43 KB LDS -> 3 blocks/CU; grid m/32 -> ~780 blocks/chunk -> ~3 resident blocks/CU.
__global__ __launch_bounds__(256) void gemm_fused(
    const ushort* __restrict__ A, const ushort* __restrict__ Bt,
    int lda, int M, int K,
    const float* __restrict__ bias, const float* __restrict__ g,
    const float* __restrict__ bvec, const ushort* __restrict__ resid,
    ushort* __restrict__ outp, int ldc, int rowOff) {
    __shared__ __align__(16) ushort As[32][72];
    __shared__ __align__(16) ushort Bs[256][72];
    __shared__ float partS[32][4];
    __shared__ float partQ[32][4];
    __shared__ float muS[32], rsS[32];
    const int tid = threadIdx.x;
    const int wave = tid >> 6, lane = tid & 63;
    const int cc = lane & 15, qd = lane >> 4;
    const int lk = qd * 8;
    const int row0 = blockIdx.x * 32;
    const int colBase = blockIdx.y * 256;
    const int wn = wave * 64;
    const int sr = tid >> 3, skc = (tid & 7) * 8;       // A staging: 1 uint4/thread
    f32x4 acc[2][4];
#pragma unroll
    for (int i = 0; i < 2; ++i)
#pragma unroll
        for (int j = 0; j < 4; ++j) acc[i][j] = (f32x4){0.f, 0.f, 0.f, 0.f};

    for (int k0 = 0; k0 < K; k0 += 64) {
        {
            uint4 va = make_uint4(0u, 0u, 0u, 0u);
            int gr = row0 + sr;
            if (gr < M) va = *(const uint4*)(A + (size_t)gr * lda + k0 + skc);
            *(uint4*)&As[sr][skc] = va;
        }
#pragma unroll
        for (int i = 0; i < 8; ++i) {
            int c = tid + i * 256;
            int r = c >> 3, kc = (c & 7) * 8;
            *(uint4*)&Bs[r][kc] = *(const uint4*)(Bt + (size_t)(colBase + r) * K + k0 + kc);
        }
        __syncthreads();
#pragma unroll
        for (int kk = 0; kk < 2; ++kk) {
            short8 af[2], bfv[4];
#pragma unroll
            for (int i = 0; i < 2; ++i) af[i] = *(const short8*)&As[i * 16 + cc][kk * 32 + lk];
#pragma unroll
            for (int j = 0; j < 4; ++j) bfv[j] = *(const short8*)&Bs[wn + j * 16 + cc][kk * 32 + lk];
#pragma unroll
            for (int i = 0; i < 2; ++i)
#pragma unroll
                for (int j = 0; j < 4; ++j)
                    acc[i][j] = __builtin_amdgcn_mfma_f32_16x16x32_bf16(af[i], bfv[j], acc[i][j], 0, 0, 0);
        }
        __syncthreads();
    }

    if (g) {
#pragma unroll
        for (int j = 0; j < 4; ++j) {
            float bcol = bias[wn + j * 16 + cc];
#pragma unroll
            for (int i = 0; i < 2; ++i)
#pragma unroll
                for (int r = 0; r < 4; ++r)
                    acc[i][j][r] = fmaxf(acc[i][j][r] + bcol, 0.f);
        }
#pragma unroll
        for (int i = 0; i < 2; ++i)
#pragma unroll
            for (int r = 0; r < 4; ++r) {
                float s = acc[i][0][r] + acc[i][1][r] + acc[i][2][r] + acc[i][3][r];
                float q = acc[i][0][r] * acc[i][0][r] + acc[i][1][r] * acc[i][1][r]
                        + acc[i][2][r] * acc[i][2][r] + acc[i][3][r] * acc[i][3][r];
#pragma unroll
                for (int off = 1; off <= 8; off <<= 1) {
                    s += __shfl_xor(s, off, 64);
                    q += __shfl_xor(q, off, 64);
                }
                if (cc == 0) {
                    int row = i * 16 + qd * 4 + r;
                    partS[row][wave] = s;
                    partQ[row][wave] = q;
                }
            }
        __syncthreads();
        if (tid < 32) {
            float S = partS[tid][0] + partS[tid][1] + partS[tid][2] + partS[tid][3];
            float Q = partQ[tid][0] + partQ[tid][1] + partQ[tid][2] + partQ[tid][3];
            float mu = S * (1.f / 256.f);
            float var = Q * (1.f / 256.f) - mu * mu;
            muS[tid] = mu;
            rsS[tid] = rsqrtf(fmaxf(var, 0.f) + LN_EPS);
        }
        __syncthreads();
#pragma unroll
        for (int i = 0; i < 2; ++i)
#pragma unroll
            for (int r = 0; r < 4; ++r) {
                int row = i * 16 + qd * 4 + r;
                int grow = row0 + row;
                if (grow >= M) continue;
                float mu = muS[row], rs = rsS[row];
                size_t base = (size_t)(rowOff + grow) * ldc;
#pragma unroll
                for (int j = 0; j < 4; ++j) {
                    int col = wn + j * 16 + cc;
                    float val = (acc[i][j][r] - mu) * rs * g[col] + bvec[col];
                    if (resid) val += b2f(resid[base + col]);
                    outp[base + col] = f2b(val);
                }
            }
    } else {
#pragma unroll
        for (int i = 0; i < 2; ++i)
#pragma unroll
            for (int r = 0; r < 4; ++r) {
                int grow = row0 + i * 16 + qd * 4 + r;
                if (grow >= M) continue;
                size_t base = (size_t)(rowOff + grow) * ldc;
#pragma unroll
                for (int j = 0; j < 4; ++j) {
                    int col = colBase + wn + j * 16 + cc;
                    outp[base + col] = f2b(acc[i][j][r]);
                }
            }
    }
}

// ---------------- edge decode (perm-ordered): z1=gelu(U[a]+V[b]+b1); z2=gelu(z1@w2); out=z2@w3+b3
__global__ __launch_bounds__(256) void edge_kernel(
    const ushort* __restrict__ uv, const int* __restrict__ dec, const int* __restrict__ perm,
    const float* __restrict__ b1, const ushort* __restrict__ w2t,
    const float* __restrict__ b2, const float* __restrict__ w3,
    const float* __restrict__ b3, float* __restrict__ outp, int M) {
    __shared__ __align__(16) ushort z1s[64][264];
    __shared__ __align__(16) ushort z2s[64][136];
    __shared__ float b1s[256], b2s[128], w3s[256];
    const int tid = threadIdx.x;
    const int wave = tid >> 6, lane = tid & 63;
    const int cc = lane & 15, qd = lane >> 4, lk = qd * 8, rr = qd * 4;
    const int e0 = blockIdx.x * 64;

    b1s[tid] = b1[tid];
    if (tid < 128) b2s[tid] = b2[tid];
    w3s[tid] = w3[tid];
    __syncthreads();

    {
        int e = tid >> 2, seg = tid & 3;
        int ge = perm[e0 + e];
        if (ge < 0) ge = 0; if (ge >= M) ge = M - 1;
        int a = dec[(size_t)ge * 2];
        int b = dec[(size_t)ge * 2 + 1];
        if (a < 0) a = 0; if (a >= N_NODES) a = N_NODES - 1;
        if (b < 0) b = 0; if (b >= N_NODES) b = N_NODES - 1;
        const ushort* up = uv + (size_t)a * 512;
        const ushort* vp = uv + (size_t)b * 512 + 256;
        int d0 = seg * 64;
#pragma unroll
        for (int c8 = 0; c8 < 8; ++c8) {
            int d = d0 + c8 * 8;
            short8 us = *(const short8*)(up + d);
            short8 vs = *(const short8*)(vp + d);
            short8 zs;
#pragma unroll
            for (int l = 0; l < 8; ++l) {
                float z = b2f((ushort)us[l]) + b2f((ushort)vs[l]) + b1s[d + l];
                zs[l] = (short)f2b(gelu_exact(z));
            }
            *(short8*)&z1s[e][d] = zs;
        }
    }
    __syncthreads();

    f32x4 acc[4][2];
#pragma unroll
    for (int i = 0; i < 4; ++i)
#pragma unroll
        for (int j = 0; j < 2; ++j) acc[i][j] = (f32x4){0.f, 0.f, 0.f, 0.f};
    const int n0 = wave * 32;
#pragma unroll
    for (int ks = 0; ks < 8; ++ks) {
        short8 af[4], bfv[2];
#pragma unroll
        for (int i = 0; i < 4; ++i) af[i] = *(const short8*)&z1s[i * 16 + cc][ks * 32 + lk];
#pragma unroll
        for (int j = 0; j < 2; ++j)
            bfv[j] = *(const short8*)(w2t + (size_t)(n0 + j * 16 + cc) * 256 + ks * 32 + lk);
#pragma unroll
        for (int i = 0; i < 4; ++i)
#pragma unroll
            for (int j = 0; j < 2; ++j)
                acc[i][j] = __builtin_amdgcn_mfma_f32_16x16x32_bf16(af[i], bfv[j], acc[i][j], 0, 0, 0);
    }
#pragma unroll
    for (int i = 0; i < 4; ++i)
#pragma unroll
        for (int j = 0; j < 2; ++j)
#pragma unroll
            for (int r = 0; r < 4; ++r) {
                int m = i * 16 + rr + r;
                int n = n0 + j * 16 + cc;
                z2s[m][n] = f2b(gelu_exact(acc[i][j][r] + b2s[n]));
            }
    __syncthreads();

    if (tid < 128) {
        int e = tid >> 1, c = tid & 1;
        float s = b3[c];
        for (int k = 0; k < 128; ++k) s += b2f(z2s[e][k]) * w3s[k * 2 + c];
        int ge = perm[e0 + e];
        if (ge >= 0 && ge < M) outp[(size_t)ge * 2 + c] = s;
    }
}

// ---------------- launch ----------------
extern "C" void kernel_launch(void* const* d_in, const int* in_sizes, int n_in,
                              void* d_out, int out_size, void* d_ws, size_t ws_size,
                              hipStream_t stream) {
    const float* x          = (const float*)d_in[0];
    const int*   edge_index = (const int*)d_in[1];
    const int*   edge_type  = (const int*)d_in[2];
    const int*   dec_edges  = (const int*)d_in[3];
    const float* W1         = (const float*)d_in[4];
    const float* root1      = (const float*)d_in[5];
    const float* b1         = (const float*)d_in[6];
    const float* W2         = (const float*)d_in[7];
    const float* root2      = (const float*)d_in[8];
    const float* b2         = (const float*)d_in[9];
    const float* ln1_g      = (const float*)d_in[10];
    const float* ln1_b      = (const float*)d_in[11];
    const float* ln2_g      = (const float*)d_in[12];
    const float* ln2_b      = (const float*)d_in[13];
    const float* mlp_w1     = (const float*)d_in[14];
    const float* mlp_b1     = (const float*)d_in[15];
    const float* mlp_w2     = (const float*)d_in[16];
    const float* mlp_b2     = (const float*)d_in[17];
    const float* mlp_w3     = (const float*)d_in[18];
    const float* mlp_b3     = (const float*)d_in[19];

    char* ws = (char*)d_ws;
    size_t off = 0;
    auto alloc = [&](size_t bytes) {
        void* p = ws + off;
        off += (bytes + 255) & ~(size_t)255;
        return p;
    };
    unsigned int* epk     = (unsigned int*)alloc((size_t)E_EDGES * 4);
    int*          row_ptr = (int*)alloc((size_t)(N_NODES + 1) * 4);
    int*          tmp     = (int*)alloc((size_t)N_NODES * 4);
    int*          bptr    = (int*)alloc((size_t)(NBUCK + 1) * 4);
    int*          perm    = (int*)alloc((size_t)M_DEC * 4);
    ushort*       B1t     = (ushort*)alloc((size_t)HID * K1 * 2);
    ushort*       B2t     = (ushort*)alloc((size_t)HID * K2 * 2);
    ushort*       wuvt    = (ushort*)alloc((size_t)512 * 256 * 2);
    ushort*       w2t     = (ushort*)alloc((size_t)128 * 256 * 2);
    ushort*       xb      = (ushort*)alloc((size_t)N_NODES * IN_DIM * 2);
    ushort*       hfin    = (ushort*)alloc((size_t)N_NODES * HID * 2);

    size_t regionOff = off;
    ushort* h1ln  = (ushort*)(ws + regionOff);
    ushort* uvbuf = h1ln;                       // alias (uv live after h1ln dead)
    size_t h1b = (((size_t)N_NODES * HID * 2) + 255) & ~(size_t)255;
    ushort* Achunk = (ushort*)(ws + regionOff + h1b);
    long long chunkB = (long long)ws_size - (long long)(regionOff + h1b);
    int chunk = 64;
    if (chunkB > 0) {
        long long c = chunkB / ((long long)K2 * 2);
        if (c > N_NODES) c = N_NODES;
        c &= ~63LL;
        if (c >= 64) chunk = (int)c;
    }

    // CSR build
    hipMemsetAsync(tmp, 0, (size_t)N_NODES * 4, stream);
    count_kernel<<<(E_EDGES + 255) / 256, 256, 0, stream>>>(edge_index, tmp);
    scan_kernel<<<1, 1024, 0, stream>>>(tmp, row_ptr, N_NODES);
    hipMemsetAsync(tmp, 0, (size_t)N_NODES * 4, stream);
    fill_kernel<<<(E_EDGES + 255) / 256, 256, 0, stream>>>(edge_index, edge_type, row_ptr, tmp, epk);

    // decode-edge locality sort
    hipMemsetAsync(tmp, 0, (size_t)NBUCK * 4, stream);
    ecount_kernel<<<(M_DEC + 255) / 256, 256, 0, stream>>>(dec_edges, tmp);
    scan_kernel<<<1, 1024, 0, stream>>>(tmp, bptr, NBUCK);
    hipMemsetAsync(tmp, 0, (size_t)NBUCK * 4, stream);
    efill_kernel<<<(M_DEC + 255) / 256, 256, 0, stream>>>(dec_edges, bptr, tmp, perm);

    // x -> bf16 table, weight packs
    xconv_kernel<<<(N_NODES * IN_DIM / 4 + 255) / 256, 256, 0, stream>>>(x, xb);
    pack_enc<<<(HID * K1 + HID * K2 + 255) / 256, 256, 0, stream>>>(root1, W1, root2, W2, B1t, B2t);
    pack_mlp<<<(512 * 256 + 128 * 256 + 255) / 256, 256, 0, stream>>>(mlp_w1, mlp_w2, wuvt, w2t);

    // conv1
    for (int n0 = 0; n0 < N_NODES; n0 += chunk) {
        int m = N_NODES - n0; if (m > chunk) m = chunk;
        agg1_kernel<<<(m + 3) / 4, 256, 0, stream>>>(xb, row_ptr, epk, Achunk, n0, m);
        gemm_fused<<<dim3((m + 31) / 32, 1), 256, 0, stream>>>(
            Achunk, B1t, K1, m, K1, b1, ln1_g, ln1_b, nullptr, h1ln, HID, n0);
    }
    // conv2 (+h1 residual)
    for (int n0 = 0; n0 < N_NODES; n0 += chunk) {
        int m = N_NODES - n0; if (m > chunk) m = chunk;
        agg2_kernel<<<(m + 3) / 4, 256, 0, stream>>>(h1ln, row_ptr, epk, Achunk, n0, m);
        gemm_fused<<<dim3((m + 31) / 32, 1), 256, 0, stream>>>(
            Achunk, B2t, K2, m, K2, b2, ln2_g, ln2_b, h1ln, hfin, HID, n0);
    }

    // U|V = hfin @ [W1_top | W1_bot]
    gemm_fused<<<dim3((N_NODES + 31) / 32, 2), 256, 0, stream>>>(
        hfin, wuvt, HID, N_NODES, HID, nullptr, nullptr, nullptr, nullptr, uvbuf, 512, 0);

    // edge decode
    edge_kernel<<<(M_DEC + 63) / 64, 256, 0, stream>>>(
        uvbuf, dec_edges, perm, mlp_b1, w2t, mlp_b2, mlp_w3, mlp_b3, (float*)d_out, M_DEC);
}

// Round 11
// 1138.175 us; speedup vs baseline: 1.2740x; 1.1050x over previous
//
#include <hip/hip_runtime.h>
#include <math.h>

typedef __attribute__((ext_vector_type(8))) short short8;
typedef __attribute__((ext_vector_type(4))) float f32x4;

#define N_NODES 50000
#define NUM_REL 8
#define IN_DIM 128
#define HID 256
#define E_EDGES 1600000
#define M_DEC 200000
#define K1 1152
#define K2 2304
#define LN_EPS 1e-5f
#define NBUCK ((N_NODES + 63) >> 6)   /* 782 */

__device__ __forceinline__ float b2f(ushort u) {
    union { unsigned int i; float f; } v; v.i = ((unsigned int)u) << 16; return v.f;
}
__device__ __forceinline__ ushort f2b(float f) {
    union { float f; unsigned int i; } v; v.f = f;
    unsigned int r = v.i + 0x7FFFu + ((v.i >> 16) & 1u);
    return (ushort)(r >> 16);
}
__device__ __forceinline__ unsigned int pk2(ushort a, ushort b) {
    return (unsigned int)a | ((unsigned int)b << 16);
}
__device__ __forceinline__ float gelu_exact(float x) {
    return 0.5f * x * (1.0f + erff(x * 0.70710678118654752f));
}

// ---------------- merged CSR + decode-sort counting ----------------
__global__ void count_all(const int* __restrict__ ei, int* __restrict__ cnt,
                          const int* __restrict__ dec, int* __restrict__ bcnt) {
    int e = blockIdx.x * 256 + threadIdx.x;
    if (e < E_EDGES) atomicAdd(&cnt[ei[E_EDGES + e]], 1);
    if (e < M_DEC) {
        int a = dec[(size_t)e * 2];
        if (a < 0) a = 0; if (a >= N_NODES) a = N_NODES - 1;
        atomicAdd(&bcnt[a >> 6], 1);
    }
}

__device__ void scan_body(const int* __restrict__ cnt, int* __restrict__ row_ptr, int n) {
    __shared__ int tsum[1024];
    const int t = threadIdx.x;
    const int CH = (n + 1023) / 1024;
    const int base = t * CH;
    int s = 0;
    for (int i = 0; i < CH; ++i) { int idx = base + i; if (idx < n) s += cnt[idx]; }
    tsum[t] = s;
    __syncthreads();
    for (int off = 1; off < 1024; off <<= 1) {
        int v = (t >= off) ? tsum[t - off] : 0;
        __syncthreads();
        tsum[t] += v;
        __syncthreads();
    }
    int run = tsum[t] - s;
    for (int i = 0; i < CH; ++i) {
        int idx = base + i;
        if (idx < n) { row_ptr[idx] = run; run += cnt[idx]; }
    }
    if (t == 1023) row_ptr[n] = tsum[1023];
}

__global__ void scan2_kernel(const int* __restrict__ cA, int* __restrict__ pA, int nA,
                             const int* __restrict__ cB, int* __restrict__ pB, int nB) {
    if (blockIdx.x == 0) scan_body(cA, pA, nA);
    else scan_body(cB, pB, nB);
}

__global__ void fill_all(const int* __restrict__ ei, const int* __restrict__ et,
                         const int* __restrict__ row_ptr, int* __restrict__ cursor,
                         unsigned int* __restrict__ epk,
                         const int* __restrict__ dec, const int* __restrict__ bptr,
                         int* __restrict__ bcur, int* __restrict__ perm) {
    int e = blockIdx.x * 256 + threadIdx.x;
    if (e < E_EDGES) {
        int src = ei[e];
        int dst = ei[E_EDGES + e];
        int r   = et[e];
        int pos = row_ptr[dst] + atomicAdd(&cursor[dst], 1);
        if (pos >= 0 && pos < E_EDGES)
            epk[pos] = (unsigned int)src | ((unsigned int)r << 16);
    }
    if (e < M_DEC) {
        int a = dec[(size_t)e * 2];
        if (a < 0) a = 0; if (a >= N_NODES) a = N_NODES - 1;
        int b = a >> 6;
        int pos = bptr[b] + atomicAdd(&bcur[b], 1);
        if (pos >= 0 && pos < M_DEC) perm[pos] = e;
    }
}

// ---------------- merged pack: xconv + enc weights + mlp weights ----------------
__global__ void pack_all(const float* __restrict__ x, ushort* __restrict__ xb,
                         const float* __restrict__ root1, const float* __restrict__ W1,
                         const float* __restrict__ root2, const float* __restrict__ W2,
                         ushort* __restrict__ B1t, ushort* __restrict__ B2t,
                         const float* __restrict__ mw1, const float* __restrict__ mw2,
                         ushort* __restrict__ wuvt, ushort* __restrict__ w2t) {
    const int XC = N_NODES * IN_DIM / 4;      // 1,600,000 (uint2 groups)
    const int N1 = HID * K1;                  // 294,912
    const int N2 = HID * K2;                  // 589,824
    const int NU = 512 * 256;                 // 131,072
    const int NW = 128 * 256;                 // 32,768
    int idx = blockIdx.x * 256 + threadIdx.x;
    if (idx < XC) {
        float4 v = *(const float4*)(x + (size_t)idx * 4);
        uint2 o;
        o.x = pk2(f2b(v.x), f2b(v.y));
        o.y = pk2(f2b(v.z), f2b(v.w));
        *(uint2*)(xb + (size_t)idx * 4) = o;
        return;
    }
    idx -= XC;
    if (idx < N1) {
        int n = idx / K1, k = idx % K1;
        float v;
        if (k < IN_DIM) v = root1[k * HID + n];
        else { int kk = k - IN_DIM; v = W1[(size_t)(kk >> 7) * IN_DIM * HID + (kk & 127) * HID + n]; }
        B1t[(size_t)n * K1 + k] = f2b(v);
        return;
    }
    idx -= N1;
    if (idx < N2) {
        int n = idx / K2, k = idx % K2;
        float v;
        if (k < HID) v = root2[k * HID + n];
        else { int kk = k - HID; v = W2[(size_t)(kk >> 8) * HID * HID + (kk & 255) * HID + n]; }
        B2t[(size_t)n * K2 + k] = f2b(v);
        return;
    }
    idx -= N2;
    if (idx < NU) {
        int n = idx / 256, k = idx % 256;
        float v = (n < 256) ? mw1[(size_t)k * 256 + n] : mw1[(size_t)(256 + k) * 256 + (n - 256)];
        wuvt[(size_t)n * 256 + k] = f2b(v);
        return;
    }
    idx -= NU;
    if (idx < NW) {
        int n = idx / 256, k = idx % 256;
        w2t[n * 256 + k] = f2b(mw2[k * 128 + n]);
    }
}

// ---------------- aggregation: wave-per-node, 4-deep unroll, named accumulators ----------
#define C1B(R) case R: aa.x += f0; aa.y += f1; goto done1_##R;
#define SW1(P, U) { float f0 = b2f((ushort)((U) & 0xFFFFu)), f1 = b2f((ushort)((U) >> 16)); \
    int r = (__builtin_amdgcn_readfirstlane((int)(P)) >> 16) & 7; \
    switch (r) { \
      case 0: a0.x += f0; a0.y += f1; c0++; break; \
      case 1: a1.x += f0; a1.y += f1; c1++; break; \
      case 2: a2.x += f0; a2.y += f1; c2++; break; \
      case 3: a3.x += f0; a3.y += f1; c3++; break; \
      case 4: a4.x += f0; a4.y += f1; c4++; break; \
      case 5: a5.x += f0; a5.y += f1; c5++; break; \
      case 6: a6.x += f0; a6.y += f1; c6++; break; \
      default: a7.x += f0; a7.y += f1; c7++; break; } }
#define E1(R) { float inv = c##R > 0 ? 1.f / (float)c##R : 0.f; \
                *(unsigned int*)(Arow + IN_DIM + R * IN_DIM + 2 * lane) = \
                    pk2(f2b(a##R.x * inv), f2b(a##R.y * inv)); }

__global__ __launch_bounds__(256) void agg1_kernel(const ushort* __restrict__ xb,
                                                   const int* __restrict__ row_ptr,
                                                   const unsigned int* __restrict__ epk,
                                                   ushort* __restrict__ Achunk, int n0, int m) {
    const int w = threadIdx.x >> 6, lane = threadIdx.x & 63;
    const int local = blockIdx.x * 4 + w;
    if (local >= m) return;
    const int n = n0 + local;
    float2 a0 = {0,0}, a1 = {0,0}, a2 = {0,0}, a3 = {0,0};
    float2 a4 = {0,0}, a5 = {0,0}, a6 = {0,0}, a7 = {0,0};
    int c0 = 0, c1 = 0, c2 = 0, c3 = 0, c4 = 0, c5 = 0, c6 = 0, c7 = 0;
    int beg = row_ptr[n], end = row_ptr[n + 1];
    if (beg < 0) beg = 0;
    if (end > E_EDGES) end = E_EDGES;
    const ushort* xbb = xb + 2 * lane;
    int e = beg;
    for (; e + 3 < end; e += 4) {
        unsigned int p0 = epk[e], p1 = epk[e + 1], p2 = epk[e + 2], p3 = epk[e + 3];
        unsigned int u0 = *(const unsigned int*)(xbb + (size_t)(p0 & 0xFFFFu) * IN_DIM);
        unsigned int u1 = *(const unsigned int*)(xbb + (size_t)(p1 & 0xFFFFu) * IN_DIM);
        unsigned int u2 = *(const unsigned int*)(xbb + (size_t)(p2 & 0xFFFFu) * IN_DIM);
        unsigned int u3 = *(const unsigned int*)(xbb + (size_t)(p3 & 0xFFFFu) * IN_DIM);
        SW1(p0, u0) SW1(p1, u1) SW1(p2, u2) SW1(p3, u3)
    }
    for (; e < end; ++e) {
        unsigned int p = epk[e];
        unsigned int u = *(const unsigned int*)(xbb + (size_t)(p & 0xFFFFu) * IN_DIM);
        SW1(p, u)
    }
    ushort* Arow = Achunk + (size_t)local * K1;
    *(unsigned int*)(Arow + 2 * lane) = *(const unsigned int*)(xb + (size_t)n * IN_DIM + 2 * lane);
    E1(0) E1(1) E1(2) E1(3) E1(4) E1(5) E1(6) E1(7)
}

#define SW2(P, U) { f32x4 f; \
    f[0] = b2f((ushort)((U).x & 0xFFFFu)); f[1] = b2f((ushort)((U).x >> 16)); \
    f[2] = b2f((ushort)((U).y & 0xFFFFu)); f[3] = b2f((ushort)((U).y >> 16)); \
    int r = (__builtin_amdgcn_readfirstlane((int)(P)) >> 16) & 7; \
    switch (r) { \
      case 0: a0 += f; c0++; break; case 1: a1 += f; c1++; break; \
      case 2: a2 += f; c2++; break; case 3: a3 += f; c3++; break; \
      case 4: a4 += f; c4++; break; case 5: a5 += f; c5++; break; \
      case 6: a6 += f; c6++; break; default: a7 += f; c7++; break; } }
#define E2(R) { float inv = c##R > 0 ? 1.f / (float)c##R : 0.f; uint2 o; \
                o.x = pk2(f2b(a##R[0] * inv), f2b(a##R[1] * inv)); \
                o.y = pk2(f2b(a##R[2] * inv), f2b(a##R[3] * inv)); \
                *(uint2*)(Arow + HID + R * HID + 4 * lane) = o; }

__global__ __launch_bounds__(256) void agg2_kernel(const ushort* __restrict__ h1,
                                                   const int* __restrict__ row_ptr,
                                                   const unsigned int* __restrict__ epk,
                                                   ushort* __restrict__ Achunk, int n0, int m) {
    const int w = threadIdx.x >> 6, lane = threadIdx.x & 63;
    const int local = blockIdx.x * 4 + w;
    if (local >= m) return;
    const int n = n0 + local;
    f32x4 a0 = {0,0,0,0}, a1 = {0,0,0,0}, a2 = {0,0,0,0}, a3 = {0,0,0,0};
    f32x4 a4 = {0,0,0,0}, a5 = {0,0,0,0}, a6 = {0,0,0,0}, a7 = {0,0,0,0};
    int c0 = 0, c1 = 0, c2 = 0, c3 = 0, c4 = 0, c5 = 0, c6 = 0, c7 = 0;
    int beg = row_ptr[n], end = row_ptr[n + 1];
    if (beg < 0) beg = 0;
    if (end > E_EDGES) end = E_EDGES;
    const ushort* hb = h1 + 4 * lane;
    int e = beg;
    for (; e + 3 < end; e += 4) {
        unsigned int p0 = epk[e], p1 = epk[e + 1], p2 = epk[e + 2], p3 = epk[e + 3];
        uint2 u0 = *(const uint2*)(hb + (size_t)(p0 & 0xFFFFu) * HID);
        uint2 u1 = *(const uint2*)(hb + (size_t)(p1 & 0xFFFFu) * HID);
        uint2 u2 = *(const uint2*)(hb + (size_t)(p2 & 0xFFFFu) * HID);
        uint2 u3 = *(const uint2*)(hb + (size_t)(p3 & 0xFFFFu) * HID);
        SW2(p0, u0) SW2(p1, u1) SW2(p2, u2) SW2(p3, u3)
    }
    for (; e < end; ++e) {
        unsigned int p = epk[e];
        uint2 u = *(const uint2*)(hb + (size_t)(p & 0xFFFFu) * HID);
        SW2(p, u)
    }
    ushort* Arow = Achunk + (size_t)local * K2;
    *(uint2*)(Arow + 4 * lane) = *(const uint2*)(h1 + (size_t)n * HID + 4 * lane);
    E2(0) E2(1) E2(2) E2(3) E2(4) E2(5) E2(6) E2(7)
}

// ---------------- GEMM 32x256 tile, A+B in LDS (padded), fused LN epilogue ----------------
__global__ __launch_bounds__(256) void gemm_fused(
    const ushort* __restrict__ A, const ushort* __restrict__ Bt,
    int lda, int M, int K,
    const float* __restrict__ bias, const float* __restrict__ g,
    const float* __restrict__ bvec, const ushort* __restrict__ resid,
    ushort* __restrict__ outp, int ldc, int rowOff) {
    __shared__ __align__(16) ushort As[32][72];
    __shared__ __align__(16) ushort Bs[256][72];
    __shared__ float partS[32][4];
    __shared__ float partQ[32][4];
    __shared__ float muS[32], rsS[32];
    const int tid = threadIdx.x;
    const int wave = tid >> 6, lane = tid & 63;
    const int cc = lane & 15, qd = lane >> 4;
    const int lk = qd * 8;
    const int row0 = blockIdx.x * 32;
    const int colBase = blockIdx.y * 256;
    const int wn = wave * 64;
    const int sr = tid >> 3, skc = (tid & 7) * 8;
    f32x4 acc[2][4];
#pragma unroll
    for (int i = 0; i < 2; ++i)
#pragma unroll
        for (int j = 0; j < 4; ++j) acc[i][j] = (f32x4){0.f, 0.f, 0.f, 0.f};

    for (int k0 = 0; k0 < K; k0 += 64) {
        {
            uint4 va = make_uint4(0u, 0u, 0u, 0u);
            int gr = row0 + sr;
            if (gr < M) va = *(const uint4*)(A + (size_t)gr * lda + k0 + skc);
            *(uint4*)&As[sr][skc] = va;
        }
#pragma unroll
        for (int i = 0; i < 8; ++i) {
            int c = tid + i * 256;
            int r = c >> 3, kc = (c & 7) * 8;
            *(uint4*)&Bs[r][kc] = *(const uint4*)(Bt + (size_t)(colBase + r) * K + k0 + kc);
        }
        __syncthreads();
#pragma unroll
        for (int kk = 0; kk < 2; ++kk) {
            short8 af[2], bfv[4];
#pragma unroll
            for (int i = 0; i < 2; ++i) af[i] = *(const short8*)&As[i * 16 + cc][kk * 32 + lk];
#pragma unroll
            for (int j = 0; j < 4; ++j) bfv[j] = *(const short8*)&Bs[wn + j * 16 + cc][kk * 32 + lk];
#pragma unroll
            for (int i = 0; i < 2; ++i)
#pragma unroll
                for (int j = 0; j < 4; ++j)
                    acc[i][j] = __builtin_amdgcn_mfma_f32_16x16x32_bf16(af[i], bfv[j], acc[i][j], 0, 0, 0);
        }
        __syncthreads();
    }

    if (g) {
#pragma unroll
        for (int j = 0; j < 4; ++j) {
            float bcol = bias[wn + j * 16 + cc];
#pragma unroll
            for (int i = 0; i < 2; ++i)
#pragma unroll
                for (int r = 0; r < 4; ++r)
                    acc[i][j][r] = fmaxf(acc[i][j][r] + bcol, 0.f);
        }
#pragma unroll
        for (int i = 0; i < 2; ++i)
#pragma unroll
            for (int r = 0; r < 4; ++r) {
                float s = acc[i][0][r] + acc[i][1][r] + acc[i][2][r] + acc[i][3][r];
                float q = acc[i][0][r] * acc[i][0][r] + acc[i][1][r] * acc[i][1][r]
                        + acc[i][2][r] * acc[i][2][r] + acc[i][3][r] * acc[i][3][r];
#pragma unroll
                for (int off = 1; off <= 8; off <<= 1) {
                    s += __shfl_xor(s, off, 64);
                    q += __shfl_xor(q, off, 64);
                }
                if (cc == 0) {
                    int row = i * 16 + qd * 4 + r;
                    partS[row][wave] = s;
                    partQ[row][wave] = q;
                }
            }
        __syncthreads();
        if (tid < 32) {
            float S = partS[tid][0] + partS[tid][1] + partS[tid][2] + partS[tid][3];
            float Q = partQ[tid][0] + partQ[tid][1] + partQ[tid][2] + partQ[tid][3];
            float mu = S * (1.f / 256.f);
            float var = Q * (1.f / 256.f) - mu * mu;
            muS[tid] = mu;
            rsS[tid] = rsqrtf(fmaxf(var, 0.f) + LN_EPS);
        }
        __syncthreads();
#pragma unroll
        for (int i = 0; i < 2; ++i)
#pragma unroll
            for (int r = 0; r < 4; ++r) {
                int row = i * 16 + qd * 4 + r;
                int grow = row0 + row;
                if (grow >= M) continue;
                float mu = muS[row], rs = rsS[row];
                size_t base = (size_t)(rowOff + grow) * ldc;
#pragma unroll
                for (int j = 0; j < 4; ++j) {
                    int col = wn + j * 16 + cc;
                    float val = (acc[i][j][r] - mu) * rs * g[col] + bvec[col];
                    if (resid) val += b2f(resid[base + col]);
                    outp[base + col] = f2b(val);
                }
            }
    } else {
#pragma unroll
        for (int i = 0; i < 2; ++i)
#pragma unroll
            for (int r = 0; r < 4; ++r) {
                int grow = row0 + i * 16 + qd * 4 + r;
                if (grow >= M) continue;
                size_t base = (size_t)(rowOff + grow) * ldc;
#pragma unroll
                for (int j = 0; j < 4; ++j) {
                    int col = colBase + wn + j * 16 + cc;
                    outp[base + col] = f2b(acc[i][j][r]);
                }
            }
    }
}

// ---------------- edge decode (perm-ordered, stage1 software-pipelined) ----------------
__global__ __launch_bounds__(256) void edge_kernel(
    const ushort* __restrict__ uv, const int* __restrict__ dec, const int* __restrict__ perm,
    const float* __restrict__ b1, const ushort* __restrict__ w2t,
    const float* __restrict__ b2, const float* __restrict__ w3,
    const float* __restrict__ b3, float* __restrict__ outp, int M) {
    __shared__ __align__(16) ushort z1s[64][264];
    __shared__ __align__(16) ushort z2s[64][136];
    __shared__ float b1s[256], b2s[128], w3s[256];
    const int tid = threadIdx.x;
    const int wave = tid >> 6, lane = tid & 63;
    const int cc = lane & 15, qd = lane >> 4, lk = qd * 8, rr = qd * 4;
    const int e0 = blockIdx.x * 64;

    b1s[tid] = b1[tid];
    if (tid < 128) b2s[tid] = b2[tid];
    w3s[tid] = w3[tid];
    __syncthreads();

    // stage1: z1 = gelu(U[a] + V[b] + b1), 4 threads/edge, 2-stage pipeline
    {
        int e = tid >> 2, seg = tid & 3;
        int ge = perm[e0 + e];
        if (ge < 0) ge = 0; if (ge >= M) ge = M - 1;
        int a = dec[(size_t)ge * 2];
        int b = dec[(size_t)ge * 2 + 1];
        if (a < 0) a = 0; if (a >= N_NODES) a = N_NODES - 1;
        if (b < 0) b = 0; if (b >= N_NODES) b = N_NODES - 1;
        const ushort* up = uv + (size_t)a * 512;
        const ushort* vp = uv + (size_t)b * 512 + 256;
        int d0 = seg * 64;
        short8 us = *(const short8*)(up + d0);
        short8 vs = *(const short8*)(vp + d0);
#pragma unroll
        for (int c8 = 0; c8 < 8; ++c8) {
            int d = d0 + c8 * 8;
            short8 usn, vsn;
            if (c8 < 7) {
                usn = *(const short8*)(up + d + 8);
                vsn = *(const short8*)(vp + d + 8);
            }
            short8 zs;
#pragma unroll
            for (int l = 0; l < 8; ++l) {
                float z = b2f((ushort)us[l]) + b2f((ushort)vs[l]) + b1s[d + l];
                zs[l] = (short)f2b(gelu_exact(z));
            }
            *(short8*)&z1s[e][d] = zs;
            us = usn; vs = vsn;
        }
    }
    __syncthreads();

    // stage2: [64,256] @ w2t[128][256]^T -> gelu -> z2s [64,128]
    f32x4 acc[4][2];
#pragma unroll
    for (int i = 0; i < 4; ++i)
#pragma unroll
        for (int j = 0; j < 2; ++j) acc[i][j] = (f32x4){0.f, 0.f, 0.f, 0.f};
    const int n0 = wave * 32;
#pragma unroll
    for (int ks = 0; ks < 8; ++ks) {
        short8 af[4], bfv[2];
#pragma unroll
        for (int i = 0; i < 4; ++i) af[i] = *(const short8*)&z1s[i * 16 + cc][ks * 32 + lk];
#pragma unroll
        for (int j = 0; j < 2; ++j)
            bfv[j] = *(const short8*)(w2t + (size_t)(n0 + j * 16 + cc) * 256 + ks * 32 + lk);
#pragma unroll
        for (int i = 0; i < 4; ++i)
#pragma unroll
            for (int j = 0; j < 2; ++j)
                acc[i][j] = __builtin_amdgcn_mfma_f32_16x16x32_bf16(af[i], bfv[j], acc[i][j], 0, 0, 0);
    }
#pragma unroll
    for (int i = 0; i < 4; ++i)
#pragma unroll
        for (int j = 0; j < 2; ++j)
#pragma unroll
            for (int r = 0; r < 4; ++r) {
                int m = i * 16 + rr + r;
                int n = n0 + j * 16 + cc;
                z2s[m][n] = f2b(gelu_exact(acc[i][j][r] + b2s[n]));
            }
    __syncthreads();

    // stage3: [64,128] @ w3[128,2] + b3, scatter to original edge index
    if (tid < 128) {
        int e = tid >> 1, c = tid & 1;
        float s = b3[c];
        for (int k = 0; k < 128; ++k) s += b2f(z2s[e][k]) * w3s[k * 2 + c];
        int ge = perm[e0 + e];
        if (ge >= 0 && ge < M) outp[(size_t)ge * 2 + c] = s;
    }
}

// ---------------- launch ----------------
extern "C" void kernel_launch(void* const* d_in, const int* in_sizes, int n_in,
                              void* d_out, int out_size, void* d_ws, size_t ws_size,
                              hipStream_t stream) {
    const float* x          = (const float*)d_in[0];
    const int*   edge_index = (const int*)d_in[1];
    const int*   edge_type  = (const int*)d_in[2];
    const int*   dec_edges  = (const int*)d_in[3];
    const float* W1         = (const float*)d_in[4];
    const float* root1      = (const float*)d_in[5];
    const float* b1         = (const float*)d_in[6];
    const float* W2         = (const float*)d_in[7];
    const float* root2      = (const float*)d_in[8];
    const float* b2         = (const float*)d_in[9];
    const float* ln1_g      = (const float*)d_in[10];
    const float* ln1_b      = (const float*)d_in[11];
    const float* ln2_g      = (const float*)d_in[12];
    const float* ln2_b      = (const float*)d_in[13];
    const float* mlp_w1     = (const float*)d_in[14];
    const float* mlp_b1     = (const float*)d_in[15];
    const float* mlp_w2     = (const float*)d_in[16];
    const float* mlp_b2     = (const float*)d_in[17];
    const float* mlp_w3     = (const float*)d_in[18];
    const float* mlp_b3     = (const float*)d_in[19];

    char* ws = (char*)d_ws;
    size_t off = 0;
    auto alloc = [&](size_t bytes) {
        void* p = ws + off;
        off += (bytes + 255) & ~(size_t)255;
        return p;
    };
    unsigned int* epk     = (unsigned int*)alloc((size_t)E_EDGES * 4);
    int*          row_ptr = (int*)alloc((size_t)(N_NODES + 1) * 4);
    int*          tmp     = (int*)alloc((size_t)(N_NODES + NBUCK) * 4);  // dst cnt | bucket cnt
    int*          tmpb    = tmp + N_NODES;
    int*          bptr    = (int*)alloc((size_t)(NBUCK + 1) * 4);
    int*          perm    = (int*)alloc((size_t)M_DEC * 4);
    ushort*       B1t     = (ushort*)alloc((size_t)HID * K1 * 2);
    ushort*       B2t     = (ushort*)alloc((size_t)HID * K2 * 2);
    ushort*       wuvt    = (ushort*)alloc((size_t)512 * 256 * 2);
    ushort*       w2t     = (ushort*)alloc((size_t)128 * 256 * 2);
    ushort*       xb      = (ushort*)alloc((size_t)N_NODES * IN_DIM * 2);
    ushort*       hfin    = (ushort*)alloc((size_t)N_NODES * HID * 2);

    size_t regionOff = off;
    ushort* h1ln  = (ushort*)(ws + regionOff);
    ushort* uvbuf = h1ln;                       // alias (uv live after h1ln dead)
    size_t h1b = (((size_t)N_NODES * HID * 2) + 255) & ~(size_t)255;
    ushort* Achunk = (ushort*)(ws + regionOff + h1b);
    long long chunkB = (long long)ws_size - (long long)(regionOff + h1b);
    int chunk = 64;
    if (chunkB > 0) {
        long long c = chunkB / ((long long)K2 * 2);
        if (c > N_NODES) c = N_NODES;
        c &= ~63LL;
        if (c >= 64) chunk = (int)c;
    }

    // CSR + sort build (merged)
    hipMemsetAsync(tmp, 0, (size_t)(N_NODES + NBUCK) * 4, stream);
    count_all<<<(E_EDGES + 255) / 256, 256, 0, stream>>>(edge_index, tmp, dec_edges, tmpb);
    scan2_kernel<<<2, 1024, 0, stream>>>(tmp, row_ptr, N_NODES, tmpb, bptr, NBUCK);
    hipMemsetAsync(tmp, 0, (size_t)(N_NODES + NBUCK) * 4, stream);
    fill_all<<<(E_EDGES + 255) / 256, 256, 0, stream>>>(edge_index, edge_type, row_ptr, tmp, epk,
                                                        dec_edges, bptr, tmpb, perm);

    // merged packs (xconv + enc + mlp)
    {
        int total = N_NODES * IN_DIM / 4 + HID * K1 + HID * K2 + 512 * 256 + 128 * 256;
        pack_all<<<(total + 255) / 256, 256, 0, stream>>>(x, xb, root1, W1, root2, W2,
                                                          B1t, B2t, mlp_w1, mlp_w2, wuvt, w2t);
    }

    // conv1
    for (int n0 = 0; n0 < N_NODES; n0 += chunk) {
        int m = N_NODES - n0; if (m > chunk) m = chunk;
        agg1_kernel<<<(m + 3) / 4, 256, 0, stream>>>(xb, row_ptr, epk, Achunk, n0, m);
        gemm_fused<<<dim3((m + 31) / 32, 1), 256, 0, stream>>>(
            Achunk, B1t, K1, m, K1, b1, ln1_g, ln1_b, nullptr, h1ln, HID, n0);
    }
    // conv2 (+h1 residual)
    for (int n0 = 0; n0 < N_NODES; n0 += chunk) {
        int m = N_NODES - n0; if (m > chunk) m = chunk;
        agg2_kernel<<<(m + 3) / 4, 256, 0, stream>>>(h1ln, row_ptr, epk, Achunk, n0, m);
        gemm_fused<<<dim3((m + 31) / 32, 1), 256, 0, stream>>>(
            Achunk, B2t, K2, m, K2, b2, ln2_g, ln2_b, h1ln, hfin, HID, n0);
    }

    // U|V = hfin @ [W1_top | W1_bot]
    gemm_fused<<<dim3((N_NODES + 31) / 32, 2), 256, 0, stream>>>(
        hfin, wuvt, HID, N_NODES, HID, nullptr, nullptr, nullptr, nullptr, uvbuf, 512, 0);

    // edge decode
    edge_kernel<<<(M_DEC + 63) / 64, 256, 0, stream>>>(
        uvbuf, dec_edges, perm, mlp_b1, w2t, mlp_b2, mlp_w3, mlp_b3, (float*)d_out, M_DEC);
}

// Round 12
// 1097.083 us; speedup vs baseline: 1.3217x; 1.0375x over previous
//
#include <hip/hip_runtime.h>
#include <math.h>

typedef __attribute__((ext_vector_type(8))) short short8;
typedef __attribute__((ext_vector_type(4))) float f32x4;
typedef __attribute__((address_space(3))) void lds_void;
typedef const __attribute__((address_space(1))) void glb_void;

#define N_NODES 50000
#define NUM_REL 8
#define IN_DIM 128
#define HID 256
#define E_EDGES 1600000
#define M_DEC 200000
#define K1 1152
#define K2 2304
#define LN_EPS 1e-5f
#define NBUCK ((N_NODES + 63) >> 6)   /* 782 */

__device__ __forceinline__ float b2f(ushort u) {
    union { unsigned int i; float f; } v; v.i = ((unsigned int)u) << 16; return v.f;
}
__device__ __forceinline__ ushort f2b(float f) {
    union { float f; unsigned int i; } v; v.f = f;
    unsigned int r = v.i + 0x7FFFu + ((v.i >> 16) & 1u);
    return (ushort)(r >> 16);
}
__device__ __forceinline__ unsigned int pk2(ushort a, ushort b) {
    return (unsigned int)a | ((unsigned int)b << 16);
}
__device__ __forceinline__ float gelu_exact(float x) {
    return 0.5f * x * (1.0f + erff(x * 0.70710678118654752f));
}

// ---------------- merged CSR + decode-sort counting ----------------
__global__ void count_all(const int* __restrict__ ei, int* __restrict__ cnt,
                          const int* __restrict__ dec, int* __restrict__ bcnt) {
    int e = blockIdx.x * 256 + threadIdx.x;
    if (e < E_EDGES) atomicAdd(&cnt[ei[E_EDGES + e]], 1);
    if (e < M_DEC) {
        int a = dec[(size_t)e * 2];
        if (a < 0) a = 0; if (a >= N_NODES) a = N_NODES - 1;
        atomicAdd(&bcnt[a >> 6], 1);
    }
}

__device__ void scan_body(const int* __restrict__ cnt, int* __restrict__ row_ptr, int n) {
    __shared__ int tsum[1024];
    const int t = threadIdx.x;
    const int CH = (n + 1023) / 1024;
    const int base = t * CH;
    int s = 0;
    for (int i = 0; i < CH; ++i) { int idx = base + i; if (idx < n) s += cnt[idx]; }
    tsum[t] = s;
    __syncthreads();
    for (int off = 1; off < 1024; off <<= 1) {
        int v = (t >= off) ? tsum[t - off] : 0;
        __syncthreads();
        tsum[t] += v;
        __syncthreads();
    }
    int run = tsum[t] - s;
    for (int i = 0; i < CH; ++i) {
        int idx = base + i;
        if (idx < n) { row_ptr[idx] = run; run += cnt[idx]; }
    }
    if (t == 1023) row_ptr[n] = tsum[1023];
}

__global__ void scan2_kernel(const int* __restrict__ cA, int* __restrict__ pA, int nA,
                             const int* __restrict__ cB, int* __restrict__ pB, int nB) {
    if (blockIdx.x == 0) scan_body(cA, pA, nA);
    else scan_body(cB, pB, nB);
}

__global__ void fill_all(const int* __restrict__ ei, const int* __restrict__ et,
                         const int* __restrict__ row_ptr, int* __restrict__ cursor,
                         unsigned int* __restrict__ epk,
                         const int* __restrict__ dec, const int* __restrict__ bptr,
                         int* __restrict__ bcur, int* __restrict__ perm) {
    int e = blockIdx.x * 256 + threadIdx.x;
    if (e < E_EDGES) {
        int src = ei[e];
        int dst = ei[E_EDGES + e];
        int r   = et[e];
        int pos = row_ptr[dst] + atomicAdd(&cursor[dst], 1);
        if (pos >= 0 && pos < E_EDGES)
            epk[pos] = (unsigned int)src | ((unsigned int)r << 16);
    }
    if (e < M_DEC) {
        int a = dec[(size_t)e * 2];
        if (a < 0) a = 0; if (a >= N_NODES) a = N_NODES - 1;
        int b = a >> 6;
        int pos = bptr[b] + atomicAdd(&bcur[b], 1);
        if (pos >= 0 && pos < M_DEC) perm[pos] = e;
    }
}

// ---------------- merged pack: xconv + enc weights + mlp weights ----------------
__global__ void pack_all(const float* __restrict__ x, ushort* __restrict__ xb,
                         const float* __restrict__ root1, const float* __restrict__ W1,
                         const float* __restrict__ root2, const float* __restrict__ W2,
                         ushort* __restrict__ B1t, ushort* __restrict__ B2t,
                         const float* __restrict__ mw1, const float* __restrict__ mw2,
                         ushort* __restrict__ wuvt, ushort* __restrict__ w2t) {
    const int XC = N_NODES * IN_DIM / 4;
    const int N1 = HID * K1;
    const int N2 = HID * K2;
    const int NU = 512 * 256;
    const int NW = 128 * 256;
    int idx = blockIdx.x * 256 + threadIdx.x;
    if (idx < XC) {
        float4 v = *(const float4*)(x + (size_t)idx * 4);
        uint2 o;
        o.x = pk2(f2b(v.x), f2b(v.y));
        o.y = pk2(f2b(v.z), f2b(v.w));
        *(uint2*)(xb + (size_t)idx * 4) = o;
        return;
    }
    idx -= XC;
    if (idx < N1) {
        int n = idx / K1, k = idx % K1;
        float v;
        if (k < IN_DIM) v = root1[k * HID + n];
        else { int kk = k - IN_DIM; v = W1[(size_t)(kk >> 7) * IN_DIM * HID + (kk & 127) * HID + n]; }
        B1t[(size_t)n * K1 + k] = f2b(v);
        return;
    }
    idx -= N1;
    if (idx < N2) {
        int n = idx / K2, k = idx % K2;
        float v;
        if (k < HID) v = root2[k * HID + n];
        else { int kk = k - HID; v = W2[(size_t)(kk >> 8) * HID * HID + (kk & 255) * HID + n]; }
        B2t[(size_t)n * K2 + k] = f2b(v);
        return;
    }
    idx -= N2;
    if (idx < NU) {
        int n = idx / 256, k = idx % 256;
        float v = (n < 256) ? mw1[(size_t)k * 256 + n] : mw1[(size_t)(256 + k) * 256 + (n - 256)];
        wuvt[(size_t)n * 256 + k] = f2b(v);
        return;
    }
    idx -= NU;
    if (idx < NW) {
        int n = idx / 256, k = idx % 256;
        w2t[n * 256 + k] = f2b(mw2[k * 128 + n]);
    }
}

// ---------------- aggregation: wave-per-node, 4-deep unroll, named accumulators ----------
#define SW1(P, U) { float f0 = b2f((ushort)((U) & 0xFFFFu)), f1 = b2f((ushort)((U) >> 16)); \
    int r = (__builtin_amdgcn_readfirstlane((int)(P)) >> 16) & 7; \
    switch (r) { \
      case 0: a0.x += f0; a0.y += f1; c0++; break; \
      case 1: a1.x += f0; a1.y += f1; c1++; break; \
      case 2: a2.x += f0; a2.y += f1; c2++; break; \
      case 3: a3.x += f0; a3.y += f1; c3++; break; \
      case 4: a4.x += f0; a4.y += f1; c4++; break; \
      case 5: a5.x += f0; a5.y += f1; c5++; break; \
      case 6: a6.x += f0; a6.y += f1; c6++; break; \
      default: a7.x += f0; a7.y += f1; c7++; break; } }
#define E1(R) { float inv = c##R > 0 ? 1.f / (float)c##R : 0.f; \
                *(unsigned int*)(Arow + IN_DIM + R * IN_DIM + 2 * lane) = \
                    pk2(f2b(a##R.x * inv), f2b(a##R.y * inv)); }

__global__ __launch_bounds__(256) void agg1_kernel(const ushort* __restrict__ xb,
                                                   const int* __restrict__ row_ptr,
                                                   const unsigned int* __restrict__ epk,
                                                   ushort* __restrict__ Achunk, int n0, int m) {
    const int w = threadIdx.x >> 6, lane = threadIdx.x & 63;
    const int local = blockIdx.x * 4 + w;
    if (local >= m) return;
    const int n = n0 + local;
    float2 a0 = {0,0}, a1 = {0,0}, a2 = {0,0}, a3 = {0,0};
    float2 a4 = {0,0}, a5 = {0,0}, a6 = {0,0}, a7 = {0,0};
    int c0 = 0, c1 = 0, c2 = 0, c3 = 0, c4 = 0, c5 = 0, c6 = 0, c7 = 0;
    int beg = row_ptr[n], end = row_ptr[n + 1];
    if (beg < 0) beg = 0;
    if (end > E_EDGES) end = E_EDGES;
    const ushort* xbb = xb + 2 * lane;
    int e = beg;
    for (; e + 3 < end; e += 4) {
        unsigned int p0 = epk[e], p1 = epk[e + 1], p2 = epk[e + 2], p3 = epk[e + 3];
        unsigned int u0 = *(const unsigned int*)(xbb + (size_t)(p0 & 0xFFFFu) * IN_DIM);
        unsigned int u1 = *(const unsigned int*)(xbb + (size_t)(p1 & 0xFFFFu) * IN_DIM);
        unsigned int u2 = *(const unsigned int*)(xbb + (size_t)(p2 & 0xFFFFu) * IN_DIM);
        unsigned int u3 = *(const unsigned int*)(xbb + (size_t)(p3 & 0xFFFFu) * IN_DIM);
        SW1(p0, u0) SW1(p1, u1) SW1(p2, u2) SW1(p3, u3)
    }
    for (; e < end; ++e) {
        unsigned int p = epk[e];
        unsigned int u = *(const unsigned int*)(xbb + (size_t)(p & 0xFFFFu) * IN_DIM);
        SW1(p, u)
    }
    ushort* Arow = Achunk + (size_t)local * K1;
    *(unsigned int*)(Arow + 2 * lane) = *(const unsigned int*)(xb + (size_t)n * IN_DIM + 2 * lane);
    E1(0) E1(1) E1(2) E1(3) E1(4) E1(5) E1(6) E1(7)
}

#define SW2(P, U) { f32x4 f; \
    f[0] = b2f((ushort)((U).x & 0xFFFFu)); f[1] = b2f((ushort)((U).x >> 16)); \
    f[2] = b2f((ushort)((U).y & 0xFFFFu)); f[3] = b2f((ushort)((U).y >> 16)); \
    int r = (__builtin_amdgcn_readfirstlane((int)(P)) >> 16) & 7; \
    switch (r) { \
      case 0: a0 += f; c0++; break; case 1: a1 += f; c1++; break; \
      case 2: a2 += f; c2++; break; case 3: a3 += f; c3++; break; \
      case 4: a4 += f; c4++; break; case 5: a5 += f; c5++; break; \
      case 6: a6 += f; c6++; break; default: a7 += f; c7++; break; } }
#define E2(R) { float inv = c##R > 0 ? 1.f / (float)c##R : 0.f; uint2 o; \
                o.x = pk2(f2b(a##R[0] * inv), f2b(a##R[1] * inv)); \
                o.y = pk2(f2b(a##R[2] * inv), f2b(a##R[3] * inv)); \
                *(uint2*)(Arow + HID + R * HID + 4 * lane) = o; }

__global__ __launch_bounds__(256) void agg2_kernel(const ushort* __restrict__ h1,
                                                   const int* __restrict__ row_ptr,
                                                   const unsigned int* __restrict__ epk,
                                                   ushort* __restrict__ Achunk, int n0, int m) {
    const int w = threadIdx.x >> 6, lane = threadIdx.x & 63;
    const int local = blockIdx.x * 4 + w;
    if (local >= m) return;
    const int n = n0 + local;
    f32x4 a0 = {0,0,0,0}, a1 = {0,0,0,0}, a2 = {0,0,0,0}, a3 = {0,0,0,0};
    f32x4 a4 = {0,0,0,0}, a5 = {0,0,0,0}, a6 = {0,0,0,0}, a7 = {0,0,0,0};
    int c0 = 0, c1 = 0, c2 = 0, c3 = 0, c4 = 0, c5 = 0, c6 = 0, c7 = 0;
    int beg = row_ptr[n], end = row_ptr[n + 1];
    if (beg < 0) beg = 0;
    if (end > E_EDGES) end = E_EDGES;
    const ushort* hb = h1 + 4 * lane;
    int e = beg;
    for (; e + 3 < end; e += 4) {
        unsigned int p0 = epk[e], p1 = epk[e + 1], p2 = epk[e + 2], p3 = epk[e + 3];
        uint2 u0 = *(const uint2*)(hb + (size_t)(p0 & 0xFFFFu) * HID);
        uint2 u1 = *(const uint2*)(hb + (size_t)(p1 & 0xFFFFu) * HID);
        uint2 u2 = *(const uint2*)(hb + (size_t)(p2 & 0xFFFFu) * HID);
        uint2 u3 = *(const uint2*)(hb + (size_t)(p3 & 0xFFFFu) * HID);
        SW2(p0, u0) SW2(p1, u1) SW2(p2, u2) SW2(p3, u3)
    }
    for (; e < end; ++e) {
        unsigned int p = epk[e];
        uint2 u = *(const uint2*)(hb + (size_t)(p & 0xFFFFu) * HID);
        SW2(p, u)
    }
    ushort* Arow = Achunk + (size_t)local * K2;
    *(uint2*)(Arow + 4 * lane) = *(const uint2*)(h1 + (size_t)n * HID + 4 * lane);
    E2(0) E2(1) E2(2) E2(3) E2(4) E2(5) E2(6) E2(7)
}

// ---------------- GEMM 32x256 tile, async global_load_lds staging, swizzled LDS ----------
// LDS image is linear (lane*16 rule); bank swizzle encoded in per-lane GLOBAL column pick:
// element (row r, colgrp g) lives at LDS ushort offset r*64 + ((g ^ (r&7))*8).
__global__ __launch_bounds__(256) void gemm_fused(
    const ushort* __restrict__ A, const ushort* __restrict__ Bt,
    int lda, int M, int K,
    const float* __restrict__ bias, const float* __restrict__ g,
    const float* __restrict__ bvec, const ushort* __restrict__ resid,
    ushort* __restrict__ outp, int ldc, int rowOff) {
    __shared__ __align__(16) ushort As[32 * 64];
    __shared__ __align__(16) ushort Bs[256 * 64];
    __shared__ float partS[32][4];
    __shared__ float partQ[32][4];
    __shared__ float muS[32], rsS[32];
    const int tid = threadIdx.x;
    const int wave = tid >> 6, lane = tid & 63;
    const int cc = lane & 15, qd = lane >> 4;
    const int row0 = blockIdx.x * 32;
    const int colBase = blockIdx.y * 256;
    const int wn = wave * 64;
    const int srow = lane >> 3;                     // 0..7 within 8-row group
    const int sgrp = (lane & 7) ^ (srow & 7);       // swizzled global col group
    f32x4 acc[2][4];
#pragma unroll
    for (int i = 0; i < 2; ++i)
#pragma unroll
        for (int j = 0; j < 4; ++j) acc[i][j] = (f32x4){0.f, 0.f, 0.f, 0.f};

    // per-lane global base addresses (k0 added per iteration)
    const ushort* Ab = A + (size_t)(row0 + wave * 8 + srow) * lda + sgrp * 8;
    const ushort* Bb = Bt + (size_t)(colBase + wn + srow) * K + sgrp * 8;
    ushort* AsW = As + wave * 8 * 64;               // wave-uniform LDS bases
    ushort* BsW = Bs + wn * 64;

    for (int k0 = 0; k0 < K; k0 += 64) {
        __builtin_amdgcn_global_load_lds((glb_void*)(Ab + k0), (lds_void*)AsW, 16, 0, 0);
#pragma unroll
        for (int j = 0; j < 8; ++j)
            __builtin_amdgcn_global_load_lds((glb_void*)(Bb + (size_t)j * 8 * K + k0),
                                             (lds_void*)(BsW + j * 8 * 64), 16, 0, 0);
        __syncthreads();
#pragma unroll
        for (int kk = 0; kk < 2; ++kk) {
            const int gsw = (((kk * 4 + qd) ^ (cc & 7)) * 8);
            short8 af[2], bfv[4];
#pragma unroll
            for (int i = 0; i < 2; ++i) af[i] = *(const short8*)&As[(i * 16 + cc) * 64 + gsw];
#pragma unroll
            for (int j = 0; j < 4; ++j) bfv[j] = *(const short8*)&Bs[(wn + j * 16 + cc) * 64 + gsw];
#pragma unroll
            for (int i = 0; i < 2; ++i)
#pragma unroll
                for (int j = 0; j < 4; ++j)
                    acc[i][j] = __builtin_amdgcn_mfma_f32_16x16x32_bf16(af[i], bfv[j], acc[i][j], 0, 0, 0);
        }
        __syncthreads();
    }

    if (g) {
#pragma unroll
        for (int j = 0; j < 4; ++j) {
            float bcol = bias[wn + j * 16 + cc];
#pragma unroll
            for (int i = 0; i < 2; ++i)
#pragma unroll
                for (int r = 0; r < 4; ++r)
                    acc[i][j][r] = fmaxf(acc[i][j][r] + bcol, 0.f);
        }
#pragma unroll
        for (int i = 0; i < 2; ++i)
#pragma unroll
            for (int r = 0; r < 4; ++r) {
                float s = acc[i][0][r] + acc[i][1][r] + acc[i][2][r] + acc[i][3][r];
                float q = acc[i][0][r] * acc[i][0][r] + acc[i][1][r] * acc[i][1][r]
                        + acc[i][2][r] * acc[i][2][r] + acc[i][3][r] * acc[i][3][r];
#pragma unroll
                for (int off = 1; off <= 8; off <<= 1) {
                    s += __shfl_xor(s, off, 64);
                    q += __shfl_xor(q, off, 64);
                }
                if (cc == 0) {
                    int row = i * 16 + qd * 4 + r;
                    partS[row][wave] = s;
                    partQ[row][wave] = q;
                }
            }
        __syncthreads();
        if (tid < 32) {
            float S = partS[tid][0] + partS[tid][1] + partS[tid][2] + partS[tid][3];
            float Q = partQ[tid][0] + partQ[tid][1] + partQ[tid][2] + partQ[tid][3];
            float mu = S * (1.f / 256.f);
            float var = Q * (1.f / 256.f) - mu * mu;
            muS[tid] = mu;
            rsS[tid] = rsqrtf(fmaxf(var, 0.f) + LN_EPS);
        }
        __syncthreads();
#pragma unroll
        for (int i = 0; i < 2; ++i)
#pragma unroll
            for (int r = 0; r < 4; ++r) {
                int row = i * 16 + qd * 4 + r;
                int grow = row0 + row;
                if (grow >= M) continue;
                float mu = muS[row], rs = rsS[row];
                size_t base = (size_t)(rowOff + grow) * ldc;
#pragma unroll
                for (int j = 0; j < 4; ++j) {
                    int col = wn + j * 16 + cc;
                    float val = (acc[i][j][r] - mu) * rs * g[col] + bvec[col];
                    if (resid) val += b2f(resid[base + col]);
                    outp[base + col] = f2b(val);
                }
            }
    } else {
#pragma unroll
        for (int i = 0; i < 2; ++i)
#pragma unroll
            for (int r = 0; r < 4; ++r) {
                int grow = row0 + i * 16 + qd * 4 + r;
                if (grow >= M) continue;
                size_t base = (size_t)(rowOff + grow) * ldc;
#pragma unroll
                for (int j = 0; j < 4; ++j) {
                    int col = colBase + wn + j * 16 + cc;
                    outp[base + col] = f2b(acc[i][j][r]);
                }
            }
    }
}

// ---------------- edge decode (perm-ordered, stage1 software-pipelined) ----------------
__global__ __launch_bounds__(256) void edge_kernel(
    const ushort* __restrict__ uv, const int* __restrict__ dec, const int* __restrict__ perm,
    const float* __restrict__ b1, const ushort* __restrict__ w2t,
    const float* __restrict__ b2, const float* __restrict__ w3,
    const float* __restrict__ b3, float* __restrict__ outp, int M) {
    __shared__ __align__(16) ushort z1s[64][264];
    __shared__ __align__(16) ushort z2s[64][136];
    __shared__ float b1s[256], b2s[128], w3s[256];
    const int tid = threadIdx.x;
    const int wave = tid >> 6, lane = tid & 63;
    const int cc = lane & 15, qd = lane >> 4, lk = qd * 8, rr = qd * 4;
    const int e0 = blockIdx.x * 64;

    b1s[tid] = b1[tid];
    if (tid < 128) b2s[tid] = b2[tid];
    w3s[tid] = w3[tid];
    __syncthreads();

    {
        int e = tid >> 2, seg = tid & 3;
        int ge = perm[e0 + e];
        if (ge < 0) ge = 0; if (ge >= M) ge = M - 1;
        int a = dec[(size_t)ge * 2];
        int b = dec[(size_t)ge * 2 + 1];
        if (a < 0) a = 0; if (a >= N_NODES) a = N_NODES - 1;
        if (b < 0) b = 0; if (b >= N_NODES) b = N_NODES - 1;
        const ushort* up = uv + (size_t)a * 512;
        const ushort* vp = uv + (size_t)b * 512 + 256;
        int d0 = seg * 64;
        short8 us = *(const short8*)(up + d0);
        short8 vs = *(const short8*)(vp + d0);
#pragma unroll
        for (int c8 = 0; c8 < 8; ++c8) {
            int d = d0 + c8 * 8;
            short8 usn, vsn;
            if (c8 < 7) {
                usn = *(const short8*)(up + d + 8);
                vsn = *(const short8*)(vp + d + 8);
            }
            short8 zs;
#pragma unroll
            for (int l = 0; l < 8; ++l) {
                float z = b2f((ushort)us[l]) + b2f((ushort)vs[l]) + b1s[d + l];
                zs[l] = (short)f2b(gelu_exact(z));
            }
            *(short8*)&z1s[e][d] = zs;
            us = usn; vs = vsn;
        }
    }
    __syncthreads();

    f32x4 acc[4][2];
#pragma unroll
    for (int i = 0; i < 4; ++i)
#pragma unroll
        for (int j = 0; j < 2; ++j) acc[i][j] = (f32x4){0.f, 0.f, 0.f, 0.f};
    const int n0 = wave * 32;
#pragma unroll
    for (int ks = 0; ks < 8; ++ks) {
        short8 af[4], bfv[2];
#pragma unroll
        for (int i = 0; i < 4; ++i) af[i] = *(const short8*)&z1s[i * 16 + cc][ks * 32 + lk];
#pragma unroll
        for (int j = 0; j < 2; ++j)
            bfv[j] = *(const short8*)(w2t + (size_t)(n0 + j * 16 + cc) * 256 + ks * 32 + lk);
#pragma unroll
        for (int i = 0; i < 4; ++i)
#pragma unroll
            for (int j = 0; j < 2; ++j)
                acc[i][j] = __builtin_amdgcn_mfma_f32_16x16x32_bf16(af[i], bfv[j], acc[i][j], 0, 0, 0);
    }
#pragma unroll
    for (int i = 0; i < 4; ++i)
#pragma unroll
        for (int j = 0; j < 2; ++j)
#pragma unroll
            for (int r = 0; r < 4; ++r) {
                int m = i * 16 + rr + r;
                int n = n0 + j * 16 + cc;
                z2s[m][n] = f2b(gelu_exact(acc[i][j][r] + b2s[n]));
            }
    __syncthreads();

    if (tid < 128) {
        int e = tid >> 1, c = tid & 1;
        float s = b3[c];
        for (int k = 0; k < 128; ++k) s += b2f(z2s[e][k]) * w3s[k * 2 + c];
        int ge = perm[e0 + e];
        if (ge >= 0 && ge < M) outp[(size_t)ge * 2 + c] = s;
    }
}

// ---------------- launch ----------------
extern "C" void kernel_launch(void* const* d_in, const int* in_sizes, int n_in,
                              void* d_out, int out_size, void* d_ws, size_t ws_size,
                              hipStream_t stream) {
    const float* x          = (const float*)d_in[0];
    const int*   edge_index = (const int*)d_in[1];
    const int*   edge_type  = (const int*)d_in[2];
    const int*   dec_edges  = (const int*)d_in[3];
    const float* W1         = (const float*)d_in[4];
    const float* root1      = (const float*)d_in[5];
    const float* b1         = (const float*)d_in[6];
    const float* W2         = (const float*)d_in[7];
    const float* root2      = (const float*)d_in[8];
    const float* b2         = (const float*)d_in[9];
    const float* ln1_g      = (const float*)d_in[10];
    const float* ln1_b      = (const float*)d_in[11];
    const float* ln2_g      = (const float*)d_in[12];
    const float* ln2_b      = (const float*)d_in[13];
    const float* mlp_w1     = (const float*)d_in[14];
    const float* mlp_b1     = (const float*)d_in[15];
    const float* mlp_w2     = (const float*)d_in[16];
    const float* mlp_b2     = (const float*)d_in[17];
    const float* mlp_w3     = (const float*)d_in[18];
    const float* mlp_b3     = (const float*)d_in[19];

    char* ws = (char*)d_ws;
    size_t off = 0;
    auto alloc = [&](size_t bytes) {
        void* p = ws + off;
        off += (bytes + 255) & ~(size_t)255;
        return p;
    };
    unsigned int* epk     = (unsigned int*)alloc((size_t)E_EDGES * 4);
    int*          row_ptr = (int*)alloc((size_t)(N_NODES + 1) * 4);
    int*          tmp     = (int*)alloc((size_t)(N_NODES + NBUCK) * 4);
    int*          tmpb    = tmp + N_NODES;
    int*          bptr    = (int*)alloc((size_t)(NBUCK + 1) * 4);
    int*          perm    = (int*)alloc((size_t)M_DEC * 4);
    ushort*       B1t     = (ushort*)alloc((size_t)HID * K1 * 2);
    ushort*       B2t     = (ushort*)alloc((size_t)HID * K2 * 2);
    ushort*       wuvt    = (ushort*)alloc((size_t)512 * 256 * 2);
    ushort*       w2t     = (ushort*)alloc((size_t)128 * 256 * 2);
    ushort*       xb      = (ushort*)alloc((size_t)N_NODES * IN_DIM * 2);
    ushort*       hfin    = (ushort*)alloc((size_t)N_NODES * HID * 2);

    size_t regionOff = off;
    ushort* h1ln  = (ushort*)(ws + regionOff);
    ushort* uvbuf = h1ln;                       // alias (uv live after h1ln dead)
    size_t h1b = (((size_t)N_NODES * HID * 2) + 255) & ~(size_t)255;
    ushort* Achunk = (ushort*)(ws + regionOff + h1b);
    long long chunkB = (long long)ws_size - (long long)(regionOff + h1b);
    int chunk = 64;
    if (chunkB > 0) {
        long long c = chunkB / ((long long)K2 * 2);
        if (c > N_NODES) c = N_NODES;
        c &= ~63LL;
        if (c >= 64) chunk = (int)c;
    }
    // conv1 rows fit 2x (K1 = K2/2) in the same buffer
    int chunk1 = chunk * 2;
    if (chunk1 > N_NODES) chunk1 = N_NODES;

    // CSR + sort build (merged)
    hipMemsetAsync(tmp, 0, (size_t)(N_NODES + NBUCK) * 4, stream);
    count_all<<<(E_EDGES + 255) / 256, 256, 0, stream>>>(edge_index, tmp, dec_edges, tmpb);
    scan2_kernel<<<2, 1024, 0, stream>>>(tmp, row_ptr, N_NODES, tmpb, bptr, NBUCK);
    hipMemsetAsync(tmp, 0, (size_t)(N_NODES + NBUCK) * 4, stream);
    fill_all<<<(E_EDGES + 255) / 256, 256, 0, stream>>>(edge_index, edge_type, row_ptr, tmp, epk,
                                                        dec_edges, bptr, tmpb, perm);

    // merged packs (xconv + enc + mlp)
    {
        int total = N_NODES * IN_DIM / 4 + HID * K1 + HID * K2 + 512 * 256 + 128 * 256;
        pack_all<<<(total + 255) / 256, 256, 0, stream>>>(x, xb, root1, W1, root2, W2,
                                                          B1t, B2t, mlp_w1, mlp_w2, wuvt, w2t);
    }

    // conv1 (usually a single full pass)
    for (int n0 = 0; n0 < N_NODES; n0 += chunk1) {
        int m = N_NODES - n0; if (m > chunk1) m = chunk1;
        agg1_kernel<<<(m + 3) / 4, 256, 0, stream>>>(xb, row_ptr, epk, Achunk, n0, m);
        gemm_fused<<<dim3((m + 31) / 32, 1), 256, 0, stream>>>(
            Achunk, B1t, K1, m, K1, b1, ln1_g, ln1_b, nullptr, h1ln, HID, n0);
    }
    // conv2 (+h1 residual)
    for (int n0 = 0; n0 < N_NODES; n0 += chunk) {
        int m = N_NODES - n0; if (m > chunk) m = chunk;
        agg2_kernel<<<(m + 3) / 4, 256, 0, stream>>>(h1ln, row_ptr, epk, Achunk, n0, m);
        gemm_fused<<<dim3((m + 31) / 32, 1), 256, 0, stream>>>(
            Achunk, B2t, K2, m, K2, b2, ln2_g, ln2_b, h1ln, hfin, HID, n0);
    }

    // U|V = hfin @ [W1_top | W1_bot]
    gemm_fused<<<dim3((N_NODES + 31) / 32, 2), 256, 0, stream>>>(
        hfin, wuvt, HID, N_NODES, HID, nullptr, nullptr, nullptr, nullptr, uvbuf, 512, 0);

    // edge decode
    edge_kernel<<<(M_DEC + 63) / 64, 256, 0, stream>>>(
        uvbuf, dec_edges, perm, mlp_b1, w2t, mlp_b2, mlp_w3, mlp_b3, (float*)d_out, M_DEC);
}

// Round 13
// 1043.531 us; speedup vs baseline: 1.3895x; 1.0513x over previous
//
#include <hip/hip_runtime.h>
#include <math.h>

typedef __attribute__((ext_vector_type(8))) short short8;
typedef __attribute__((ext_vector_type(4))) float f32x4;
typedef __attribute__((address_space(3))) void lds_void;
typedef const __attribute__((address_space(1))) void glb_void;

#define N_NODES 50000
#define NUM_REL 8
#define IN_DIM 128
#define HID 256
#define E_EDGES 1600000
#define M_DEC 200000
#define K1 1152
#define K2 2304
#define LN_EPS 1e-5f
#define NBUCK ((N_NODES + 63) >> 6)   /* 782 */

__device__ __forceinline__ float b2f(ushort u) {
    union { unsigned int i; float f; } v; v.i = ((unsigned int)u) << 16; return v.f;
}
__device__ __forceinline__ ushort f2b(float f) {
    union { float f; unsigned int i; } v; v.f = f;
    unsigned int r = v.i + 0x7FFFu + ((v.i >> 16) & 1u);
    return (ushort)(r >> 16);
}
__device__ __forceinline__ unsigned int pk2(ushort a, ushort b) {
    return (unsigned int)a | ((unsigned int)b << 16);
}
// fast gelu (tanh form, native exp/rcp): |err| <= ~3e-3 absolute, fine at 2% rel tol
__device__ __forceinline__ float gelu_fast(float x) {
    float y = 1.5957691216f * (x + 0.044715f * x * x * x);   // 2*sqrt(2/pi)*(...)
    float e = __expf(y);
    float t = 1.f - 2.f * __builtin_amdgcn_rcpf(e + 1.f);    // tanh(y/2... ) — note y holds 2*arg
    return 0.5f * x * (1.f + t);
}

// ---------------- merged CSR + decode-sort counting ----------------
__global__ void count_all(const int* __restrict__ ei, int* __restrict__ cnt,
                          const int* __restrict__ dec, int* __restrict__ bcnt) {
    int e = blockIdx.x * 256 + threadIdx.x;
    if (e < E_EDGES) atomicAdd(&cnt[ei[E_EDGES + e]], 1);
    if (e < M_DEC) {
        int a = dec[(size_t)e * 2];
        if (a < 0) a = 0; if (a >= N_NODES) a = N_NODES - 1;
        atomicAdd(&bcnt[a >> 6], 1);
    }
}

__device__ void scan_body(const int* __restrict__ cnt, int* __restrict__ row_ptr, int n) {
    __shared__ int tsum[1024];
    const int t = threadIdx.x;
    const int CH = (n + 1023) / 1024;
    const int base = t * CH;
    int s = 0;
    for (int i = 0; i < CH; ++i) { int idx = base + i; if (idx < n) s += cnt[idx]; }
    tsum[t] = s;
    __syncthreads();
    for (int off = 1; off < 1024; off <<= 1) {
        int v = (t >= off) ? tsum[t - off] : 0;
        __syncthreads();
        tsum[t] += v;
        __syncthreads();
    }
    int run = tsum[t] - s;
    for (int i = 0; i < CH; ++i) {
        int idx = base + i;
        if (idx < n) { row_ptr[idx] = run; run += cnt[idx]; }
    }
    if (t == 1023) row_ptr[n] = tsum[1023];
}

__global__ void scan2_kernel(const int* __restrict__ cA, int* __restrict__ pA, int nA,
                             const int* __restrict__ cB, int* __restrict__ pB, int nB) {
    if (blockIdx.x == 0) scan_body(cA, pA, nA);
    else scan_body(cB, pB, nB);
}

__global__ void fill_all(const int* __restrict__ ei, const int* __restrict__ et,
                         const int* __restrict__ row_ptr, int* __restrict__ cursor,
                         unsigned int* __restrict__ epk,
                         const int* __restrict__ dec, const int* __restrict__ bptr,
                         int* __restrict__ bcur, int* __restrict__ perm) {
    int e = blockIdx.x * 256 + threadIdx.x;
    if (e < E_EDGES) {
        int src = ei[e];
        int dst = ei[E_EDGES + e];
        int r   = et[e];
        int pos = row_ptr[dst] + atomicAdd(&cursor[dst], 1);
        if (pos >= 0 && pos < E_EDGES)
            epk[pos] = (unsigned int)src | ((unsigned int)r << 16);
    }
    if (e < M_DEC) {
        int a = dec[(size_t)e * 2];
        if (a < 0) a = 0; if (a >= N_NODES) a = N_NODES - 1;
        int b = a >> 6;
        int pos = bptr[b] + atomicAdd(&bcur[b], 1);
        if (pos >= 0 && pos < M_DEC) perm[pos] = e;
    }
}

// ---------------- merged pack: xconv + enc weights + mlp weights ----------------
__global__ void pack_all(const float* __restrict__ x, ushort* __restrict__ xb,
                         const float* __restrict__ root1, const float* __restrict__ W1,
                         const float* __restrict__ root2, const float* __restrict__ W2,
                         ushort* __restrict__ B1t, ushort* __restrict__ B2t,
                         const float* __restrict__ mw1, const float* __restrict__ mw2,
                         ushort* __restrict__ wuvt, ushort* __restrict__ w2t) {
    const int XC = N_NODES * IN_DIM / 4;
    const int N1 = HID * K1;
    const int N2 = HID * K2;
    const int NU = 512 * 256;
    const int NW = 128 * 256;
    int idx = blockIdx.x * 256 + threadIdx.x;
    if (idx < XC) {
        float4 v = *(const float4*)(x + (size_t)idx * 4);
        uint2 o;
        o.x = pk2(f2b(v.x), f2b(v.y));
        o.y = pk2(f2b(v.z), f2b(v.w));
        *(uint2*)(xb + (size_t)idx * 4) = o;
        return;
    }
    idx -= XC;
    if (idx < N1) {
        int n = idx / K1, k = idx % K1;
        float v;
        if (k < IN_DIM) v = root1[k * HID + n];
        else { int kk = k - IN_DIM; v = W1[(size_t)(kk >> 7) * IN_DIM * HID + (kk & 127) * HID + n]; }
        B1t[(size_t)n * K1 + k] = f2b(v);
        return;
    }
    idx -= N1;
    if (idx < N2) {
        int n = idx / K2, k = idx % K2;
        float v;
        if (k < HID) v = root2[k * HID + n];
        else { int kk = k - HID; v = W2[(size_t)(kk >> 8) * HID * HID + (kk & 255) * HID + n]; }
        B2t[(size_t)n * K2 + k] = f2b(v);
        return;
    }
    idx -= N2;
    if (idx < NU) {
        int n = idx / 256, k = idx % 256;
        float v = (n < 256) ? mw1[(size_t)k * 256 + n] : mw1[(size_t)(256 + k) * 256 + (n - 256)];
        wuvt[(size_t)n * 256 + k] = f2b(v);
        return;
    }
    idx -= NU;
    if (idx < NW) {
        int n = idx / 256, k = idx % 256;
        w2t[n * 256 + k] = f2b(mw2[k * 128 + n]);
    }
}

// ---------------- aggregation: wave-per-node, 8-deep unroll, named accumulators ----------
#define SW1(P, U) { float f0 = b2f((ushort)((U) & 0xFFFFu)), f1 = b2f((ushort)((U) >> 16)); \
    int r = (__builtin_amdgcn_readfirstlane((int)(P)) >> 16) & 7; \
    switch (r) { \
      case 0: a0.x += f0; a0.y += f1; c0++; break; \
      case 1: a1.x += f0; a1.y += f1; c1++; break; \
      case 2: a2.x += f0; a2.y += f1; c2++; break; \
      case 3: a3.x += f0; a3.y += f1; c3++; break; \
      case 4: a4.x += f0; a4.y += f1; c4++; break; \
      case 5: a5.x += f0; a5.y += f1; c5++; break; \
      case 6: a6.x += f0; a6.y += f1; c6++; break; \
      default: a7.x += f0; a7.y += f1; c7++; break; } }
#define E1(R) { float inv = c##R > 0 ? 1.f / (float)c##R : 0.f; \
                *(unsigned int*)(Arow + IN_DIM + R * IN_DIM + 2 * lane) = \
                    pk2(f2b(a##R.x * inv), f2b(a##R.y * inv)); }

__global__ __launch_bounds__(256) void agg1_kernel(const ushort* __restrict__ xb,
                                                   const int* __restrict__ row_ptr,
                                                   const unsigned int* __restrict__ epk,
                                                   ushort* __restrict__ Achunk, int n0, int m) {
    const int w = threadIdx.x >> 6, lane = threadIdx.x & 63;
    const int local = blockIdx.x * 4 + w;
    if (local >= m) return;
    const int n = n0 + local;
    float2 a0 = {0,0}, a1 = {0,0}, a2 = {0,0}, a3 = {0,0};
    float2 a4 = {0,0}, a5 = {0,0}, a6 = {0,0}, a7 = {0,0};
    int c0 = 0, c1 = 0, c2 = 0, c3 = 0, c4 = 0, c5 = 0, c6 = 0, c7 = 0;
    int beg = row_ptr[n], end = row_ptr[n + 1];
    if (beg < 0) beg = 0;
    if (end > E_EDGES) end = E_EDGES;
    const ushort* xbb = xb + 2 * lane;
    int e = beg;
    for (; e + 7 < end; e += 8) {
        unsigned int p0 = epk[e],     p1 = epk[e + 1], p2 = epk[e + 2], p3 = epk[e + 3];
        unsigned int p4 = epk[e + 4], p5 = epk[e + 5], p6 = epk[e + 6], p7 = epk[e + 7];
        unsigned int u0 = *(const unsigned int*)(xbb + (size_t)(p0 & 0xFFFFu) * IN_DIM);
        unsigned int u1 = *(const unsigned int*)(xbb + (size_t)(p1 & 0xFFFFu) * IN_DIM);
        unsigned int u2 = *(const unsigned int*)(xbb + (size_t)(p2 & 0xFFFFu) * IN_DIM);
        unsigned int u3 = *(const unsigned int*)(xbb + (size_t)(p3 & 0xFFFFu) * IN_DIM);
        unsigned int u4 = *(const unsigned int*)(xbb + (size_t)(p4 & 0xFFFFu) * IN_DIM);
        unsigned int u5 = *(const unsigned int*)(xbb + (size_t)(p5 & 0xFFFFu) * IN_DIM);
        unsigned int u6 = *(const unsigned int*)(xbb + (size_t)(p6 & 0xFFFFu) * IN_DIM);
        unsigned int u7 = *(const unsigned int*)(xbb + (size_t)(p7 & 0xFFFFu) * IN_DIM);
        SW1(p0, u0) SW1(p1, u1) SW1(p2, u2) SW1(p3, u3)
        SW1(p4, u4) SW1(p5, u5) SW1(p6, u6) SW1(p7, u7)
    }
    for (; e < end; ++e) {
        unsigned int p = epk[e];
        unsigned int u = *(const unsigned int*)(xbb + (size_t)(p & 0xFFFFu) * IN_DIM);
        SW1(p, u)
    }
    ushort* Arow = Achunk + (size_t)local * K1;
    *(unsigned int*)(Arow + 2 * lane) = *(const unsigned int*)(xb + (size_t)n * IN_DIM + 2 * lane);
    E1(0) E1(1) E1(2) E1(3) E1(4) E1(5) E1(6) E1(7)
}

#define SW2(P, U) { f32x4 f; \
    f[0] = b2f((ushort)((U).x & 0xFFFFu)); f[1] = b2f((ushort)((U).x >> 16)); \
    f[2] = b2f((ushort)((U).y & 0xFFFFu)); f[3] = b2f((ushort)((U).y >> 16)); \
    int r = (__builtin_amdgcn_readfirstlane((int)(P)) >> 16) & 7; \
    switch (r) { \
      case 0: a0 += f; c0++; break; case 1: a1 += f; c1++; break; \
      case 2: a2 += f; c2++; break; case 3: a3 += f; c3++; break; \
      case 4: a4 += f; c4++; break; case 5: a5 += f; c5++; break; \
      case 6: a6 += f; c6++; break; default: a7 += f; c7++; break; } }
#define E2(R) { float inv = c##R > 0 ? 1.f / (float)c##R : 0.f; uint2 o; \
                o.x = pk2(f2b(a##R[0] * inv), f2b(a##R[1] * inv)); \
                o.y = pk2(f2b(a##R[2] * inv), f2b(a##R[3] * inv)); \
                *(uint2*)(Arow + HID + R * HID + 4 * lane) = o; }

__global__ __launch_bounds__(256) void agg2_kernel(const ushort* __restrict__ h1,
                                                   const int* __restrict__ row_ptr,
                                                   const unsigned int* __restrict__ epk,
                                                   ushort* __restrict__ Achunk, int n0, int m) {
    const int w = threadIdx.x >> 6, lane = threadIdx.x & 63;
    const int local = blockIdx.x * 4 + w;
    if (local >= m) return;
    const int n = n0 + local;
    f32x4 a0 = {0,0,0,0}, a1 = {0,0,0,0}, a2 = {0,0,0,0}, a3 = {0,0,0,0};
    f32x4 a4 = {0,0,0,0}, a5 = {0,0,0,0}, a6 = {0,0,0,0}, a7 = {0,0,0,0};
    int c0 = 0, c1 = 0, c2 = 0, c3 = 0, c4 = 0, c5 = 0, c6 = 0, c7 = 0;
    int beg = row_ptr[n], end = row_ptr[n + 1];
    if (beg < 0) beg = 0;
    if (end > E_EDGES) end = E_EDGES;
    const ushort* hb = h1 + 4 * lane;
    int e = beg;
    for (; e + 7 < end; e += 8) {
        unsigned int p0 = epk[e],     p1 = epk[e + 1], p2 = epk[e + 2], p3 = epk[e + 3];
        unsigned int p4 = epk[e + 4], p5 = epk[e + 5], p6 = epk[e + 6], p7 = epk[e + 7];
        uint2 u0 = *(const uint2*)(hb + (size_t)(p0 & 0xFFFFu) * HID);
        uint2 u1 = *(const uint2*)(hb + (size_t)(p1 & 0xFFFFu) * HID);
        uint2 u2 = *(const uint2*)(hb + (size_t)(p2 & 0xFFFFu) * HID);
        uint2 u3 = *(const uint2*)(hb + (size_t)(p3 & 0xFFFFu) * HID);
        uint2 u4 = *(const uint2*)(hb + (size_t)(p4 & 0xFFFFu) * HID);
        uint2 u5 = *(const uint2*)(hb + (size_t)(p5 & 0xFFFFu) * HID);
        uint2 u6 = *(const uint2*)(hb + (size_t)(p6 & 0xFFFFu) * HID);
        uint2 u7 = *(const uint2*)(hb + (size_t)(p7 & 0xFFFFu) * HID);
        SW2(p0, u0) SW2(p1, u1) SW2(p2, u2) SW2(p3, u3)
        SW2(p4, u4) SW2(p5, u5) SW2(p6, u6) SW2(p7, u7)
    }
    for (; e < end; ++e) {
        unsigned int p = epk[e];
        uint2 u = *(const uint2*)(hb + (size_t)(p & 0xFFFFu) * HID);
        SW2(p, u)
    }
    ushort* Arow = Achunk + (size_t)local * K2;
    *(uint2*)(Arow + 4 * lane) = *(const uint2*)(h1 + (size_t)n * HID + 4 * lane);
    E2(0) E2(1) E2(2) E2(3) E2(4) E2(5) E2(6) E2(7)
}

// ---------------- GEMM 32x256 tile, async global_load_lds staging, swizzled LDS ----------
__global__ __launch_bounds__(256) void gemm_fused(
    const ushort* __restrict__ A, const ushort* __restrict__ Bt,
    int lda, int M, int K,
    const float* __restrict__ bias, const float* __restrict__ g,
    const float* __restrict__ bvec, const ushort* __restrict__ resid,
    ushort* __restrict__ outp, int ldc, int rowOff) {
    __shared__ __align__(16) ushort As[32 * 64];
    __shared__ __align__(16) ushort Bs[256 * 64];
    __shared__ float partS[32][4];
    __shared__ float partQ[32][4];
    __shared__ float muS[32], rsS[32];
    const int tid = threadIdx.x;
    const int wave = tid >> 6, lane = tid & 63;
    const int cc = lane & 15, qd = lane >> 4;
    const int row0 = blockIdx.x * 32;
    const int colBase = blockIdx.y * 256;
    const int wn = wave * 64;
    const int srow = lane >> 3;
    const int sgrp = (lane & 7) ^ (srow & 7);
    f32x4 acc[2][4];
#pragma unroll
    for (int i = 0; i < 2; ++i)
#pragma unroll
        for (int j = 0; j < 4; ++j) acc[i][j] = (f32x4){0.f, 0.f, 0.f, 0.f};

    const ushort* Ab = A + (size_t)(row0 + wave * 8 + srow) * lda + sgrp * 8;
    const ushort* Bb = Bt + (size_t)(colBase + wn + srow) * K + sgrp * 8;
    ushort* AsW = As + wave * 8 * 64;
    ushort* BsW = Bs + wn * 64;

    for (int k0 = 0; k0 < K; k0 += 64) {
        __builtin_amdgcn_global_load_lds((glb_void*)(Ab + k0), (lds_void*)AsW, 16, 0, 0);
#pragma unroll
        for (int j = 0; j < 8; ++j)
            __builtin_amdgcn_global_load_lds((glb_void*)(Bb + (size_t)j * 8 * K + k0),
                                             (lds_void*)(BsW + j * 8 * 64), 16, 0, 0);
        __syncthreads();
#pragma unroll
        for (int kk = 0; kk < 2; ++kk) {
            const int gsw = (((kk * 4 + qd) ^ (cc & 7)) * 8);
            short8 af[2], bfv[4];
#pragma unroll
            for (int i = 0; i < 2; ++i) af[i] = *(const short8*)&As[(i * 16 + cc) * 64 + gsw];
#pragma unroll
            for (int j = 0; j < 4; ++j) bfv[j] = *(const short8*)&Bs[(wn + j * 16 + cc) * 64 + gsw];
#pragma unroll
            for (int i = 0; i < 2; ++i)
#pragma unroll
                for (int j = 0; j < 4; ++j)
                    acc[i][j] = __builtin_amdgcn_mfma_f32_16x16x32_bf16(af[i], bfv[j], acc[i][j], 0, 0, 0);
        }
        __syncthreads();
    }

    if (g) {
#pragma unroll
        for (int j = 0; j < 4; ++j) {
            float bcol = bias[wn + j * 16 + cc];
#pragma unroll
            for (int i = 0; i < 2; ++i)
#pragma unroll
                for (int r = 0; r < 4; ++r)
                    acc[i][j][r] = fmaxf(acc[i][j][r] + bcol, 0.f);
        }
#pragma unroll
        for (int i = 0; i < 2; ++i)
#pragma unroll
            for (int r = 0; r < 4; ++r) {
                float s = acc[i][0][r] + acc[i][1][r] + acc[i][2][r] + acc[i][3][r];
                float q = acc[i][0][r] * acc[i][0][r] + acc[i][1][r] * acc[i][1][r]
                        + acc[i][2][r] * acc[i][2][r] + acc[i][3][r] * acc[i][3][r];
#pragma unroll
                for (int off = 1; off <= 8; off <<= 1) {
                    s += __shfl_xor(s, off, 64);
                    q += __shfl_xor(q, off, 64);
                }
                if (cc == 0) {
                    int row = i * 16 + qd * 4 + r;
                    partS[row][wave] = s;
                    partQ[row][wave] = q;
                }
            }
        __syncthreads();
        if (tid < 32) {
            float S = partS[tid][0] + partS[tid][1] + partS[tid][2] + partS[tid][3];
            float Q = partQ[tid][0] + partQ[tid][1] + partQ[tid][2] + partQ[tid][3];
            float mu = S * (1.f / 256.f);
            float var = Q * (1.f / 256.f) - mu * mu;
            muS[tid] = mu;
            rsS[tid] = rsqrtf(fmaxf(var, 0.f) + LN_EPS);
        }
        __syncthreads();
#pragma unroll
        for (int i = 0; i < 2; ++i)
#pragma unroll
            for (int r = 0; r < 4; ++r) {
                int row = i * 16 + qd * 4 + r;
                int grow = row0 + row;
                if (grow >= M) continue;
                float mu = muS[row], rs = rsS[row];
                size_t base = (size_t)(rowOff + grow) * ldc;
#pragma unroll
                for (int j = 0; j < 4; ++j) {
                    int col = wn + j * 16 + cc;
                    float val = (acc[i][j][r] - mu) * rs * g[col] + bvec[col];
                    if (resid) val += b2f(resid[base + col]);
                    outp[base + col] = f2b(val);
                }
            }
    } else {
#pragma unroll
        for (int i = 0; i < 2; ++i)
#pragma unroll
            for (int r = 0; r < 4; ++r) {
                int grow = row0 + i * 16 + qd * 4 + r;
                if (grow >= M) continue;
                size_t base = (size_t)(rowOff + grow) * ldc;
#pragma unroll
                for (int j = 0; j < 4; ++j) {
                    int col = colBase + wn + j * 16 + cc;
                    outp[base + col] = f2b(acc[i][j][r]);
                }
            }
    }
}

// ---------------- edge decode: batch register loads (16 in flight), fast gelu ------------
__global__ __launch_bounds__(256) void edge_kernel(
    const ushort* __restrict__ uv, const int* __restrict__ dec, const int* __restrict__ perm,
    const float* __restrict__ b1, const ushort* __restrict__ w2t,
    const float* __restrict__ b2, const float* __restrict__ w3,
    const float* __restrict__ b3, float* __restrict__ outp, int M) {
    __shared__ __align__(16) ushort z1s[64][264];
    __shared__ __align__(16) ushort z2s[64][136];
    __shared__ float b1s[256], b2s[128], w3s[256];
    const int tid = threadIdx.x;
    const int wave = tid >> 6, lane = tid & 63;
    const int cc = lane & 15, qd = lane >> 4, lk = qd * 8, rr = qd * 4;
    const int e0 = blockIdx.x * 64;

    b1s[tid] = b1[tid];
    if (tid < 128) b2s[tid] = b2[tid];
    w3s[tid] = w3[tid];
    __syncthreads();

    // stage1: z1 = gelu(U[a] + V[b] + b1), 4 threads/edge, all 16 loads issued up front
    {
        int e = tid >> 2, seg = tid & 3;
        int ge = perm[e0 + e];
        if (ge < 0) ge = 0; if (ge >= M) ge = M - 1;
        int a = dec[(size_t)ge * 2];
        int b = dec[(size_t)ge * 2 + 1];
        if (a < 0) a = 0; if (a >= N_NODES) a = N_NODES - 1;
        if (b < 0) b = 0; if (b >= N_NODES) b = N_NODES - 1;
        const ushort* up = uv + (size_t)a * 512 + seg * 64;
        const ushort* vp = uv + (size_t)b * 512 + 256 + seg * 64;
        short8 us[8], vs[8];
#pragma unroll
        for (int j = 0; j < 8; ++j) us[j] = *(const short8*)(up + j * 8);
#pragma unroll
        for (int j = 0; j < 8; ++j) vs[j] = *(const short8*)(vp + j * 8);
        int d0 = seg * 64;
#pragma unroll
        for (int j = 0; j < 8; ++j) {
            int d = d0 + j * 8;
            short8 zs;
#pragma unroll
            for (int l = 0; l < 8; ++l) {
                float z = b2f((ushort)us[j][l]) + b2f((ushort)vs[j][l]) + b1s[d + l];
                zs[l] = (short)f2b(gelu_fast(z));
            }
            *(short8*)&z1s[e][d] = zs;
        }
    }
    __syncthreads();

    // stage2: [64,256] @ w2t[128][256]^T -> gelu -> z2s [64,128]
    f32x4 acc[4][2];
#pragma unroll
    for (int i = 0; i < 4; ++i)
#pragma unroll
        for (int j = 0; j < 2; ++j) acc[i][j] = (f32x4){0.f, 0.f, 0.f, 0.f};
    const int n0 = wave * 32;
#pragma unroll
    for (int ks = 0; ks < 8; ++ks) {
        short8 af[4], bfv[2];
#pragma unroll
        for (int i = 0; i < 4; ++i) af[i] = *(const short8*)&z1s[i * 16 + cc][ks * 32 + lk];
#pragma unroll
        for (int j = 0; j < 2; ++j)
            bfv[j] = *(const short8*)(w2t + (size_t)(n0 + j * 16 + cc) * 256 + ks * 32 + lk);
#pragma unroll
        for (int i = 0; i < 4; ++i)
#pragma unroll
            for (int j = 0; j < 2; ++j)
                acc[i][j] = __builtin_amdgcn_mfma_f32_16x16x32_bf16(af[i], bfv[j], acc[i][j], 0, 0, 0);
    }
#pragma unroll
    for (int i = 0; i < 4; ++i)
#pragma unroll
        for (int j = 0; j < 2; ++j)
#pragma unroll
            for (int r = 0; r < 4; ++r) {
                int m = i * 16 + rr + r;
                int n = n0 + j * 16 + cc;
                z2s[m][n] = f2b(gelu_fast(acc[i][j][r] + b2s[n]));
            }
    __syncthreads();

    // stage3: [64,128] @ w3[128,2] + b3, scatter to original edge index
    if (tid < 128) {
        int e = tid >> 1, c = tid & 1;
        float s = b3[c];
        for (int k = 0; k < 128; ++k) s += b2f(z2s[e][k]) * w3s[k * 2 + c];
        int ge = perm[e0 + e];
        if (ge >= 0 && ge < M) outp[(size_t)ge * 2 + c] = s;
    }
}

// ---------------- launch ----------------
extern "C" void kernel_launch(void* const* d_in, const int* in_sizes, int n_in,
                              void* d_out, int out_size, void* d_ws, size_t ws_size,
                              hipStream_t stream) {
    const float* x          = (const float*)d_in[0];
    const int*   edge_index = (const int*)d_in[1];
    const int*   edge_type  = (const int*)d_in[2];
    const int*   dec_edges  = (const int*)d_in[3];
    const float* W1         = (const float*)d_in[4];
    const float* root1      = (const float*)d_in[5];
    const float* b1         = (const float*)d_in[6];
    const float* W2         = (const float*)d_in[7];
    const float* root2      = (const float*)d_in[8];
    const float* b2         = (const float*)d_in[9];
    const float* ln1_g      = (const float*)d_in[10];
    const float* ln1_b      = (const float*)d_in[11];
    const float* ln2_g      = (const float*)d_in[12];
    const float* ln2_b      = (const float*)d_in[13];
    const float* mlp_w1     = (const float*)d_in[14];
    const float* mlp_b1     = (const float*)d_in[15];
    const float* mlp_w2     = (const float*)d_in[16];
    const float* mlp_b2     = (const float*)d_in[17];
    const float* mlp_w3     = (const float*)d_in[18];
    const float* mlp_b3     = (const float*)d_in[19];

    char* ws = (char*)d_ws;
    size_t off = 0;
    auto alloc = [&](size_t bytes) {
        void* p = ws + off;
        off += (bytes + 255) & ~(size_t)255;
        return p;
    };
    unsigned int* epk     = (unsigned int*)alloc((size_t)E_EDGES * 4);
    int*          row_ptr = (int*)alloc((size_t)(N_NODES + 1) * 4);
    int*          tmp     = (int*)alloc((size_t)(N_NODES + NBUCK) * 4);
    int*          tmpb    = tmp + N_NODES;
    int*          bptr    = (int*)alloc((size_t)(NBUCK + 1) * 4);
    int*          perm    = (int*)alloc((size_t)M_DEC * 4);
    ushort*       B1t     = (ushort*)alloc((size_t)HID * K1 * 2);
    ushort*       B2t     = (ushort*)alloc((size_t)HID * K2 * 2);
    ushort*       wuvt    = (ushort*)alloc((size_t)512 * 256 * 2);
    ushort*       w2t     = (ushort*)alloc((size_t)128 * 256 * 2);
    ushort*       xb      = (ushort*)alloc((size_t)N_NODES * IN_DIM * 2);
    ushort*       hfin    = (ushort*)alloc((size_t)N_NODES * HID * 2);

    size_t regionOff = off;
    ushort* h1ln  = (ushort*)(ws + regionOff);
    ushort* uvbuf = h1ln;
    size_t h1b = (((size_t)N_NODES * HID * 2) + 255) & ~(size_t)255;
    ushort* Achunk = (ushort*)(ws + regionOff + h1b);
    long long chunkB = (long long)ws_size - (long long)(regionOff + h1b);
    int chunk = 64;
    if (chunkB > 0) {
        long long c = chunkB / ((long long)K2 * 2);
        if (c > N_NODES) c = N_NODES;
        c &= ~63LL;
        if (c >= 64) chunk = (int)c;
    }
    int chunk1 = chunk * 2;
    if (chunk1 > N_NODES) chunk1 = N_NODES;

    // CSR + sort build (merged)
    hipMemsetAsync(tmp, 0, (size_t)(N_NODES + NBUCK) * 4, stream);
    count_all<<<(E_EDGES + 255) / 256, 256, 0, stream>>>(edge_index, tmp, dec_edges, tmpb);
    scan2_kernel<<<2, 1024, 0, stream>>>(tmp, row_ptr, N_NODES, tmpb, bptr, NBUCK);
    hipMemsetAsync(tmp, 0, (size_t)(N_NODES + NBUCK) * 4, stream);
    fill_all<<<(E_EDGES + 255) / 256, 256, 0, stream>>>(edge_index, edge_type, row_ptr, tmp, epk,
                                                        dec_edges, bptr, tmpb, perm);

    // merged packs (xconv + enc + mlp)
    {
        int total = N_NODES * IN_DIM / 4 + HID * K1 + HID * K2 + 512 * 256 + 128 * 256;
        pack_all<<<(total + 255) / 256, 256, 0, stream>>>(x, xb, root1, W1, root2, W2,
                                                          B1t, B2t, mlp_w1, mlp_w2, wuvt, w2t);
    }

    // conv1
    for (int n0 = 0; n0 < N_NODES; n0 += chunk1) {
        int m = N_NODES - n0; if (m > chunk1) m = chunk1;
        agg1_kernel<<<(m + 3) / 4, 256, 0, stream>>>(xb, row_ptr, epk, Achunk, n0, m);
        gemm_fused<<<dim3((m + 31) / 32, 1), 256, 0, stream>>>(
            Achunk, B1t, K1, m, K1, b1, ln1_g, ln1_b, nullptr, h1ln, HID, n0);
    }
    // conv2 (+h1 residual)
    for (int n0 = 0; n0 < N_NODES; n0 += chunk) {
        int m = N_NODES - n0; if (m > chunk) m = chunk;
        agg2_kernel<<<(m + 3) / 4, 256, 0, stream>>>(h1ln, row_ptr, epk, Achunk, n0, m);
        gemm_fused<<<dim3((m + 31) / 32, 1), 256, 0, stream>>>(
            Achunk, B2t, K2, m, K2, b2, ln2_g, ln2_b, h1ln, hfin, HID, n0);
    }

    // U|V = hfin @ [W1_top | W1_bot]
    gemm_fused<<<dim3((N_NODES + 31) / 32, 2), 256, 0, stream>>>(
        hfin, wuvt, HID, N_NODES, HID, nullptr, nullptr, nullptr, nullptr, uvbuf, 512, 0);

    // edge decode
    edge_kernel<<<(M_DEC + 63) / 64, 256, 0, stream>>>(
        uvbuf, dec_edges, perm, mlp_b1, w2t, mlp_b2, mlp_w3, mlp_b3, (float*)d_out, M_DEC);
}